// Round 14
// baseline (357.328 us; speedup 1.0000x reference)
//
#include <hip/hip_runtime.h>
#include <hip/hip_bf16.h>
#include <hip/hip_fp16.h>
#include <hip/hip_fp8.h>

#define NN 50000
#define NE 1200000
#define DIN 128
#define HDIM 64
#define NG 64
#define EPSV 1e-5f
#define SCANBLK 1024
#define NB ((NN + SCANBLK - 1) / SCANBLK)

typedef __attribute__((ext_vector_type(8))) short bfrag;   // 8 bf16 = 4 VGPRs
typedef __attribute__((ext_vector_type(4))) float ffrag;   // 4 fp32 acc

__device__ __forceinline__ float b2f(const __hip_bfloat16 v) { return __bfloat162float(v); }
__device__ __forceinline__ float bu2f(unsigned short u) {
    return __uint_as_float(((unsigned int)u) << 16);
}
__device__ __forceinline__ unsigned short f2bu(float f) {
    __hip_bfloat16 b = __float2bfloat16(f);
    return *(unsigned short*)&b;
}
__device__ __forceinline__ unsigned int packbf(float a, float b) {
    return (unsigned int)f2bu(a) | ((unsigned int)f2bu(b) << 16);
}
__device__ __forceinline__ unsigned int f2f8(float x) {
    __hip_fp8_e4m3 t(x);
    return (unsigned int)t.__x;
}
__device__ __forceinline__ float f82f(unsigned int b) {
    __hip_fp8_e4m3 t;
    t.__x = (__hip_fp8_storage_t)b;
    return (float)t;
}

__device__ __forceinline__ float ldf(const void* p, size_t idx, int isbf16) {
    return isbf16 ? b2f(((const __hip_bfloat16*)p)[idx]) : ((const float*)p)[idx];
}

__device__ __forceinline__ int xcc_id() {
    int x;
    asm volatile("s_getreg_b32 %0, hwreg(HW_REG_XCC_ID)" : "=s"(x));
    return x & 7;
}

// ---------------- dtype detection ----------------
__global__ void k_detect(const unsigned short* __restrict__ x, int* __restrict__ cnt, int n) {
    int i = blockIdx.x * 256 + threadIdx.x;
    if (i < n) {
        unsigned short u = x[i];
        if (((u >> 7) & 0xFF) == 0xFF) atomicAdd(cnt, 1);
    }
}

// ---------------- param offsets ----------------
#define PW_WIN   0
#define PW_BIN   8192
#define PW_GCNW  8256
#define PW_GCNB  16448
#define PW_GCNBN 16576
#define PW_SWL   17088
#define PW_SWR   25280
#define PW_SB    33472
#define PW_SBN   33600
#define PW_F1W   34112
#define PW_F1B   42304
#define PW_BN1   42368
#define PW_F2W   42624
#define PW_F2B   44672
#define PW_BN2   44704
#define PW_F3W   44832
#define PW_F3B   44864
#define PW_TOT   44865
#define WT_TOT   (6 * 4096)

// grid partition of k_front
#define NDEG   ((NE + 1023) / 1024)                 // 1172
#define NGEMM  ((NN + 63) / 64)                     // 782
#define NCVT   ((PW_TOT + WT_TOT + 255) / 256)      // 272
#define NCOUNT ((NN + 1023) / 1024)                 // 49

struct PSrc { const void* p[17]; };

// ============ fused front-end: degree | in_mfma | cvt | gcount ============
// All parts independent; only reads of prior-launch outputs (cnt) + raw inputs.
__global__ __launch_bounds__(256) void k_front(
        PSrc s, const int* __restrict__ cnt,
        const int* __restrict__ dst, int* __restrict__ indeg8, int* __restrict__ rank,
        const void* __restrict__ x, unsigned short* __restrict__ hb,
        unsigned char* __restrict__ hf8,
        float* __restrict__ prm, unsigned short* __restrict__ wt,
        const int* __restrict__ batch, int* __restrict__ gcnt) {
    __shared__ unsigned short smem[2 * 64 * 136];   // 34 KB union
    int bid = blockIdx.x;
    int t = threadIdx.x;

    if (bid < NDEG) {
        // ---- Part A: XCD-local degree counting ----
        int xc = xcc_id();
        int* my = indeg8 + (size_t)xc * NN;
        int hi = xc << 16;
        int e0 = (bid * 256 + t) * 4;
        if (e0 + 3 < NE) {
            int4 d = *(const int4*)&dst[e0];
            int r0 = atomicAdd(&my[d.x], 1);
            int r1 = atomicAdd(&my[d.y], 1);
            int r2 = atomicAdd(&my[d.z], 1);
            int r3 = atomicAdd(&my[d.w], 1);
            *(int4*)&rank[e0] = make_int4(hi | r0, hi | r1, hi | r2, hi | r3);
        } else {
            for (int e = e0; e < NE; ++e) rank[e] = hi | atomicAdd(&my[dst[e]], 1);
        }
    } else if (bid < NDEG + NGEMM) {
        // ---- Part B: input MFMA GEMM, self-loading W_in/b_in raw ----
        unsigned short (*Xs)[136] = (unsigned short (*)[136])smem;
        unsigned short (*Wt)[136] = (unsigned short (*)[136])(smem + 64 * 136);
        int v0 = (bid - NDEG) * 64;
        int f16 = (*cnt < 4) ? 1 : 0;
        const void* xw = s.p[0];   // W_in raw [128][64]
#pragma unroll
        for (int j = 0; j < 32; ++j) {
            int i = t + 256 * j;
            int r = i >> 7, c = i & 127;
            int v = v0 + r;
            Xs[r][c] = (v < NN) ? f2bu(ldf(x, (size_t)v * DIN + c, f16)) : 0;
            // Wt[nn][kk] = W_in[kk][nn]
            Wt[i >> 7][i & 127] = f2bu(ldf(xw, (size_t)(i & 127) * 64 + (i >> 7), f16));
        }
        __syncthreads();
        int w = t >> 6, lane = t & 63;
        int m = lane & 15, kq = lane >> 4;
        int lr = w * 16 + m;
        bfrag a[4];
#pragma unroll
        for (int s2 = 0; s2 < 4; ++s2) a[s2] = *(const bfrag*)&Xs[lr][s2 * 32 + kq * 8];
        ffrag zf = {0.0f, 0.0f, 0.0f, 0.0f};
        ffrag acc[4] = {zf, zf, zf, zf};
#pragma unroll
        for (int nt = 0; nt < 4; ++nt)
#pragma unroll
            for (int s2 = 0; s2 < 4; ++s2) {
                bfrag b = *(const bfrag*)&Wt[nt * 16 + m][s2 * 32 + kq * 8];
                acc[nt] = __builtin_amdgcn_mfma_f32_16x16x32_bf16(a[s2], b, acc[nt], 0, 0, 0);
            }
#pragma unroll
        for (int nt = 0; nt < 4; ++nt) {
            int f = nt * 16 + m;
            float bb = ldf(s.p[1], f, f16);   // b_in raw
#pragma unroll
            for (int r = 0; r < 4; ++r) {
                int v = v0 + w * 16 + kq * 4 + r;
                if (v < NN) {
                    float y = fmaxf(acc[nt][r] + bb, 0.0f);
                    hb[(size_t)v * 64 + f] = f2bu(y);
                    hf8[(size_t)v * 64 + f] = (unsigned char)f2f8(y);
                }
            }
        }
    } else if (bid < NDEG + NGEMM + NCVT) {
        // ---- Part D: param conversion + layer-weight transposes ----
        const int offs[18] = {PW_WIN, PW_BIN, PW_GCNW, PW_GCNB, PW_GCNBN, PW_SWL, PW_SWR,
                              PW_SB, PW_SBN, PW_F1W, PW_F1B, PW_BN1, PW_F2W, PW_F2B,
                              PW_BN2, PW_F3W, PW_F3B, PW_TOT};
        int i = (bid - NDEG - NGEMM) * 256 + t;
        int f = (*cnt < 4) ? 1 : 0;
        if (i < PW_TOT) {
            int seg = 0;
            while (i >= offs[seg + 1]) ++seg;
            prm[i] = ldf(s.p[seg], i - offs[seg], f);
        } else if (i < PW_TOT + WT_TOT) {
            int j = i - PW_TOT;
            int mtx = j >> 12, idx = j & 4095;
            int nn = idx >> 6, kk = idx & 63;
            const void* wp = (mtx % 3 == 0) ? s.p[2] : (mtx % 3 == 1) ? s.p[5] : s.p[6];
            wt[j] = f2bu(ldf(wp, (size_t)(mtx / 3) * 4096 + kk * 64 + nn, f));
        }
    } else {
        // ---- Part C: graph-size histogram ----
        int* hist = (int*)smem;
        if (t < NG) hist[t] = 0;
        __syncthreads();
        int v = (bid - NDEG - NGEMM - NCVT) * 1024 + t;
#pragma unroll
        for (int j = 0; j < 4; ++j, v += 256)
            if (v < NN) atomicAdd(&hist[batch[v]], 1);
        __syncthreads();
        if (t < NG) {
            int c = hist[t];
            if (c) atomicAdd(&gcnt[t], c);
        }
    }
}

// ---- scan1: sum 8 copies -> degree; overwrite copies with exclusive per-copy offsets ----
__global__ __launch_bounds__(256) void k_scan1(int* __restrict__ indeg8,
                                               int* __restrict__ rowptr,
                                               float* __restrict__ dinv,
                                               float* __restrict__ cinv,
                                               int* __restrict__ bsum, int n) {
    __shared__ int wsum[4];
    int t = threadIdx.x;
    int wid = t >> 6, lane = t & 63;
    int base = blockIdx.x * SCANBLK;
    int i0 = base + t * 4;
    int d[4];
#pragma unroll
    for (int j = 0; j < 4; ++j) {
        int i = i0 + j;
        int dsum = 0;
        if (i < n) {
            int run = 0;
#pragma unroll
            for (int c = 0; c < 8; ++c) {
                size_t o = (size_t)c * NN + i;
                int val = indeg8[o];
                indeg8[o] = run;
                run += val;
            }
            dsum = run;
            float fd = (float)dsum;
            dinv[i] = rsqrtf(fd + 1.0f);
            cinv[i] = 1.0f / fmaxf(fd, 1.0f);
        }
        d[j] = dsum;
    }
    int s = d[0] + d[1] + d[2] + d[3];
    int x = s;
#pragma unroll
    for (int off = 1; off < 64; off <<= 1) {
        int y = __shfl_up(x, off, 64);
        if (lane >= off) x += y;
    }
    if (lane == 63) wsum[wid] = x;
    __syncthreads();
    int woff = 0;
#pragma unroll
    for (int j = 0; j < 4; ++j) if (j < wid) woff += wsum[j];
    int excl = woff + x - s;
    int run = 0;
#pragma unroll
    for (int j = 0; j < 4; ++j) {
        int i = i0 + j;
        if (i < n) rowptr[i] = excl + run;
        run += d[j];
    }
    if (t == 0) bsum[blockIdx.x] = wsum[0] + wsum[1] + wsum[2] + wsum[3];
}

__global__ void k_scan2(const int* __restrict__ bsum, int* __restrict__ boff,
                        int* __restrict__ rowptr, int nb, int n) {
    int lane = threadIdx.x;
    int s = (lane < nb) ? bsum[lane] : 0;
    int x = s;
#pragma unroll
    for (int off = 1; off < 64; off <<= 1) {
        int y = __shfl_up(x, off, 64);
        if (lane >= off) x += y;
    }
    if (lane < nb) boff[lane] = x - s;
    if (lane == nb - 1) rowptr[n] = s;
}

__global__ __launch_bounds__(256) void k_fill(const int* __restrict__ src,
                                              const int* __restrict__ dst,
                                              const int* __restrict__ rowptr,
                                              const int* __restrict__ boff,
                                              const int* __restrict__ indeg8,
                                              const int* __restrict__ rank,
                                              int* __restrict__ csr_src, int E) {
    int e0 = (blockIdx.x * 256 + threadIdx.x) * 4;
    if (e0 + 3 < E) {
        int4 d = *(const int4*)&dst[e0];
        int4 r = *(const int4*)&rank[e0];
        int4 sc = *(const int4*)&src[e0];
        csr_src[rowptr[d.x] + boff[d.x >> 10] + indeg8[(size_t)(r.x >> 16) * NN + d.x]
                + (r.x & 0xFFFF)] = sc.x;
        csr_src[rowptr[d.y] + boff[d.y >> 10] + indeg8[(size_t)(r.y >> 16) * NN + d.y]
                + (r.y & 0xFFFF)] = sc.y;
        csr_src[rowptr[d.z] + boff[d.z >> 10] + indeg8[(size_t)(r.z >> 16) * NN + d.z]
                + (r.z & 0xFFFF)] = sc.z;
        csr_src[rowptr[d.w] + boff[d.w >> 10] + indeg8[(size_t)(r.w >> 16) * NN + d.w]
                + (r.w & 0xFFFF)] = sc.w;
    } else {
        for (int e = e0; e < E; ++e) {
            int d = dst[e];
            int r = rank[e];
            csr_src[rowptr[d] + boff[d >> 10] + indeg8[(size_t)(r >> 16) * NN + d]
                    + (r & 0xFFFF)] = src[e];
        }
    }
}

// ---------------- MFMA fused layer GEMM ----------------
__global__ __launch_bounds__(256) void k_layer_mfma(
        const unsigned int* __restrict__ gb, const void* __restrict__ selfp, int selfPacked,
        const unsigned short* __restrict__ W0t, const unsigned short* __restrict__ Wlt,
        const unsigned short* __restrict__ Wrt,
        const float* __restrict__ b0, const float* __restrict__ bs,
        const float* __restrict__ bn0, const float* __restrict__ bns,
        const float* __restrict__ dinv,
        unsigned int* __restrict__ outp, unsigned short* __restrict__ outf8, int n) {
    __shared__ unsigned int Ag[64][68];
    __shared__ unsigned int Su[64][68];
    __shared__ unsigned short Wt0[64][72];
    __shared__ unsigned short Wt1[64][72];
    int t = threadIdx.x;
    int v0 = blockIdx.x * 64;

    uint4 z4 = make_uint4(0, 0, 0, 0);
#pragma unroll
    for (int j = 0; j < 4; ++j) {
        int c = t + 256 * j;
        int r = c >> 4, cq = c & 15;
        int v = v0 + r;
        uint4 val = (v < n) ? *(const uint4*)&gb[(size_t)v * 64 + cq * 4] : z4;
        *(uint4*)&Ag[r][cq * 4] = val;
    }
    if (selfPacked) {
        const unsigned int* sp = (const unsigned int*)selfp;
#pragma unroll
        for (int j = 0; j < 4; ++j) {
            int c = t + 256 * j;
            int r = c >> 4, cq = c & 15;
            int v = v0 + r;
            uint4 val = (v < n) ? *(const uint4*)&sp[(size_t)v * 64 + cq * 4] : z4;
            *(uint4*)&Su[r][cq * 4] = val;
        }
    } else {
        const unsigned int* sp = (const unsigned int*)selfp;
#pragma unroll
        for (int j = 0; j < 2; ++j) {
            int c = t + 256 * j;
            int r = c >> 3, cq = c & 7;
            int v = v0 + r;
            uint4 val = (v < n) ? *(const uint4*)&sp[(size_t)v * 32 + cq * 4] : z4;
            *(uint4*)&Su[r][cq * 4] = val;
        }
    }
#pragma unroll
    for (int j = 0; j < 2; ++j) {
        int c = t + 256 * j;
        int r = c >> 3, cq = c & 7;
        *(uint4*)&Wt0[r][cq * 8] = *(const uint4*)&W0t[r * 64 + cq * 8];
        *(uint4*)&Wt1[r][cq * 8] = *(const uint4*)&Wlt[r * 64 + cq * 8];
    }
    __syncthreads();

    int w = t >> 6, lane = t & 63;
    int m = lane & 15, kq = lane >> 4;
    int lr = w * 16 + m;

    bfrag ag[2], as_[2], asl[2];
#pragma unroll
    for (int s = 0; s < 2; ++s) {
        uint4 u0 = *(const uint4*)&Ag[lr][s * 32 + kq * 8];
        uint4 u1 = *(const uint4*)&Ag[lr][s * 32 + kq * 8 + 4];
        unsigned int uu[8] = {u0.x, u0.y, u0.z, u0.w, u1.x, u1.y, u1.z, u1.w};
#pragma unroll
        for (int j = 0; j < 8; ++j) {
            ag[s][j] = (short)(uu[j] & 0xFFFF);
            as_[s][j] = (short)(uu[j] >> 16);
        }
        if (selfPacked) {
            uint4 s0 = *(const uint4*)&Su[lr][s * 32 + kq * 8];
            uint4 s1 = *(const uint4*)&Su[lr][s * 32 + kq * 8 + 4];
            unsigned int su[8] = {s0.x, s0.y, s0.z, s0.w, s1.x, s1.y, s1.z, s1.w};
#pragma unroll
            for (int j = 0; j < 8; ++j) asl[s][j] = (short)(su[j] >> 16);
        } else {
            const unsigned short* srow = (const unsigned short*)&Su[lr][0];
            asl[s] = *(const bfrag*)(srow + s * 32 + kq * 8);
        }
    }

    ffrag zf = {0.0f, 0.0f, 0.0f, 0.0f};
    ffrag accg[4] = {zf, zf, zf, zf};
    ffrag accs[4] = {zf, zf, zf, zf};
#pragma unroll
    for (int nt = 0; nt < 4; ++nt) {
#pragma unroll
        for (int s = 0; s < 2; ++s) {
            bfrag b0f = *(const bfrag*)&Wt0[nt * 16 + m][s * 32 + kq * 8];
            accg[nt] = __builtin_amdgcn_mfma_f32_16x16x32_bf16(ag[s], b0f, accg[nt], 0, 0, 0);
            bfrag b1f = *(const bfrag*)&Wt1[nt * 16 + m][s * 32 + kq * 8];
            accs[nt] = __builtin_amdgcn_mfma_f32_16x16x32_bf16(as_[s], b1f, accs[nt], 0, 0, 0);
        }
    }
    __syncthreads();
#pragma unroll
    for (int j = 0; j < 2; ++j) {
        int c = t + 256 * j;
        int r = c >> 3, cq = c & 7;
        *(uint4*)&Wt0[r][cq * 8] = *(const uint4*)&Wrt[r * 64 + cq * 8];
    }
    __syncthreads();
#pragma unroll
    for (int nt = 0; nt < 4; ++nt) {
#pragma unroll
        for (int s = 0; s < 2; ++s) {
            bfrag brf = *(const bfrag*)&Wt0[nt * 16 + m][s * 32 + kq * 8];
            accs[nt] = __builtin_amdgcn_mfma_f32_16x16x32_bf16(asl[s], brf, accs[nt], 0, 0, 0);
        }
    }
#pragma unroll
    for (int nt = 0; nt < 4; ++nt) {
        int f = nt * 16 + m;
        float bg = b0[f], bv = bs[f];
        float g0 = bn0[f], g1 = bn0[64 + f], g2 = bn0[128 + f];
        float g3 = rsqrtf(bn0[192 + f] + EPSV);
        float s0 = bns[f], s1 = bns[64 + f], s2 = bns[128 + f];
        float s3 = rsqrtf(bns[192 + f] + EPSV);
#pragma unroll
        for (int r = 0; r < 4; ++r) {
            int v = v0 + w * 16 + kq * 4 + r;
            if (v < n) {
                float yg = fmaxf((accg[nt][r] + bg - g2) * g3 * g0 + g1, 0.0f);
                float ys = fmaxf((accs[nt][r] + bv - s2) * s3 * s0 + s1, 0.0f);
                outp[(size_t)v * 64 + f] = packbf(yg, ys);
                if (outf8) {
                    float dv = dinv[v];
                    outf8[(size_t)v * 64 + f] =
                        (unsigned short)(f2f8(yg * dv) | (f2f8(ys) << 8));
                }
            }
        }
    }
}

// ------- quarter-wave dual gathers, fp8 operands -------
__global__ __launch_bounds__(256) void k_gather0(const unsigned char* __restrict__ hf8,
                                                 const unsigned short* __restrict__ hb,
                                                 const float* __restrict__ dinv,
                                                 const float* __restrict__ cinv,
                                                 const int* __restrict__ rowptr,
                                                 const int* __restrict__ boff,
                                                 const int* __restrict__ csr_src,
                                                 unsigned int* __restrict__ gb, int n) {
    int wid = threadIdx.x >> 6, lane = threadIdx.x & 63;
    int v = blockIdx.x * 4 + wid;
    if (v >= n) return;
    int q = lane >> 4, ql = lane & 15;
    int beg = rowptr[v] + boff[v >> 10];
    int end = rowptr[v + 1] + boff[(v + 1) >> 10];
    float accg[4] = {0, 0, 0, 0}, accs[4] = {0, 0, 0, 0};
    int i = beg;
    for (; i + 8 <= end; i += 8) {
        int s0 = csr_src[i + q];
        int s1 = csr_src[i + 4 + q];
        unsigned int u0 = *(const unsigned int*)&hf8[(size_t)s0 * 64 + ql * 4];
        unsigned int u1 = *(const unsigned int*)&hf8[(size_t)s1 * 64 + ql * 4];
        float w0 = dinv[s0], w1 = dinv[s1];
#pragma unroll
        for (int k = 0; k < 4; ++k) {
            float x0 = f82f((u0 >> (8 * k)) & 0xFF);
            float x1 = f82f((u1 >> (8 * k)) & 0xFF);
            accg[k] = fmaf(x0, w0, accg[k]); accs[k] += x0;
            accg[k] = fmaf(x1, w1, accg[k]); accs[k] += x1;
        }
    }
    for (; i < end; i += 4) {
        int e = i + q;
        if (e < end) {
            int s = csr_src[e];
            unsigned int u = *(const unsigned int*)&hf8[(size_t)s * 64 + ql * 4];
            float w = dinv[s];
#pragma unroll
            for (int k = 0; k < 4; ++k) {
                float x = f82f((u >> (8 * k)) & 0xFF);
                accg[k] = fmaf(x, w, accg[k]); accs[k] += x;
            }
        }
    }
#pragma unroll
    for (int k = 0; k < 4; ++k) {
        accg[k] += __shfl_xor(accg[k], 16, 64);
        accg[k] += __shfl_xor(accg[k], 32, 64);
        accs[k] += __shfl_xor(accs[k], 16, 64);
        accs[k] += __shfl_xor(accs[k], 32, 64);
    }
    if (q == 0) {
        float dv = dinv[v], cv = cinv[v];
        uint2 us = *(const uint2*)&hb[(size_t)v * 64 + ql * 4];
        float sx[4] = {bu2f((unsigned short)(us.x & 0xFFFF)), bu2f((unsigned short)(us.x >> 16)),
                       bu2f((unsigned short)(us.y & 0xFFFF)), bu2f((unsigned short)(us.y >> 16))};
        unsigned int pk[4];
#pragma unroll
        for (int k = 0; k < 4; ++k) {
            float yg = dv * (accg[k] + dv * sx[k]);
            float ys = cv * accs[k];
            pk[k] = packbf(yg, ys);
        }
        *(uint4*)&gb[(size_t)v * 64 + ql * 4] = make_uint4(pk[0], pk[1], pk[2], pk[3]);
    }
}

__global__ __launch_bounds__(256) void k_gather1(const unsigned short* __restrict__ Cf8,
                                                 const unsigned int* __restrict__ Cb,
                                                 const float* __restrict__ dinv,
                                                 const float* __restrict__ cinv,
                                                 const int* __restrict__ rowptr,
                                                 const int* __restrict__ boff,
                                                 const int* __restrict__ csr_src,
                                                 unsigned int* __restrict__ gb, int n) {
    int wid = threadIdx.x >> 6, lane = threadIdx.x & 63;
    int v = blockIdx.x * 4 + wid;
    if (v >= n) return;
    int q = lane >> 4, ql = lane & 15;
    int beg = rowptr[v] + boff[v >> 10];
    int end = rowptr[v + 1] + boff[(v + 1) >> 10];
    float accg[4] = {0, 0, 0, 0}, accs[4] = {0, 0, 0, 0};
    int i = beg;
    for (; i + 8 <= end; i += 8) {
        int s0 = csr_src[i + q];
        int s1 = csr_src[i + 4 + q];
        uint2 u0 = *(const uint2*)&Cf8[(size_t)s0 * 64 + ql * 4];
        uint2 u1 = *(const uint2*)&Cf8[(size_t)s1 * 64 + ql * 4];
        unsigned int p0[4] = {u0.x & 0xFFFF, u0.x >> 16, u0.y & 0xFFFF, u0.y >> 16};
        unsigned int p1[4] = {u1.x & 0xFFFF, u1.x >> 16, u1.y & 0xFFFF, u1.y >> 16};
#pragma unroll
        for (int k = 0; k < 4; ++k) {
            accg[k] += f82f(p0[k] & 0xFF) + f82f(p1[k] & 0xFF);
            accs[k] += f82f(p0[k] >> 8) + f82f(p1[k] >> 8);
        }
    }
    for (; i < end; i += 4) {
        int e = i + q;
        if (e < end) {
            int s = csr_src[e];
            uint2 u = *(const uint2*)&Cf8[(size_t)s * 64 + ql * 4];
            unsigned int p[4] = {u.x & 0xFFFF, u.x >> 16, u.y & 0xFFFF, u.y >> 16};
#pragma unroll
            for (int k = 0; k < 4; ++k) {
                accg[k] += f82f(p[k] & 0xFF);
                accs[k] += f82f(p[k] >> 8);
            }
        }
    }
#pragma unroll
    for (int k = 0; k < 4; ++k) {
        accg[k] += __shfl_xor(accg[k], 16, 64);
        accg[k] += __shfl_xor(accg[k], 32, 64);
        accs[k] += __shfl_xor(accs[k], 16, 64);
        accs[k] += __shfl_xor(accs[k], 32, 64);
    }
    if (q == 0) {
        float dv = dinv[v], cv = cinv[v];
        uint4 us = *(const uint4*)&Cb[(size_t)v * 64 + ql * 4];
        unsigned int su[4] = {us.x, us.y, us.z, us.w};
        unsigned int pk[4];
#pragma unroll
        for (int k = 0; k < 4; ++k) {
            float yg = dv * (accg[k] + dv * bu2f((unsigned short)(su[k] & 0xFFFF)));
            float ys = cv * accs[k];
            pk[k] = packbf(yg, ys);
        }
        *(uint4*)&gb[(size_t)v * 64 + ql * 4] = make_uint4(pk[0], pk[1], pk[2], pk[3]);
    }
}

// ---------------- pooling over packed bf16 final feats ----------------
__global__ __launch_bounds__(256) void k_pool2(const unsigned int* __restrict__ X2,
                                               const int* __restrict__ batch,
                                               float* __restrict__ pooled, int n) {
    int wid = threadIdx.x >> 6, lane = threadIdx.x & 63;
    int v0 = blockIdx.x * 64 + wid * 16;
    float ag = 0.0f, as = 0.0f;
    int g = -1;
    for (int j = 0; j < 16; ++j) {
        int v = v0 + j;
        if (v >= n) break;
        int b = batch[v];
        if (b != g) {
            if (g >= 0) {
                atomicAdd(&pooled[g * 128 + lane], ag);
                atomicAdd(&pooled[g * 128 + 64 + lane], as);
            }
            g = b; ag = 0.0f; as = 0.0f;
        }
        unsigned int u = X2[(size_t)v * 64 + lane];
        ag += bu2f((unsigned short)(u & 0xFFFF));
        as += bu2f((unsigned short)(u >> 16));
    }
    if (g >= 0) {
        atomicAdd(&pooled[g * 128 + lane], ag);
        atomicAdd(&pooled[g * 128 + 64 + lane], as);
    }
}

// ---------------- head MLP (single block) ----------------
__global__ __launch_bounds__(256) void k_head(const float* __restrict__ pooled,
                                              const int* __restrict__ gcnt,
                                              const float* __restrict__ P_,
                                              const int* __restrict__ cnt,
                                              void* __restrict__ out) {
    const float* f1W = P_ + PW_F1W;
    const float* f1b = P_ + PW_F1B;
    const float* bn1 = P_ + PW_BN1;
    const float* f2W = P_ + PW_F2W;
    const float* f2b = P_ + PW_F2B;
    const float* bn2 = P_ + PW_BN2;
    const float* f3W = P_ + PW_F3W;
    const float* f3b = P_ + PW_F3B;
    __shared__ float P[64][128];
    __shared__ float Z1[64][64];
    __shared__ float Z2[64][32];
    int t = threadIdx.x;
    for (int i = t; i < 64 * 128; i += 256) {
        int g = i >> 7;
        float c = fmaxf((float)gcnt[g], 1.0f);
        P[g][i & 127] = pooled[i] / c;
    }
    __syncthreads();
    for (int o = t; o < 64 * 64; o += 256) {
        int g = o >> 6, f = o & 63;
        float acc = 0.0f;
        for (int c = 0; c < 128; ++c) acc = fmaf(P[g][c], f1W[c * 64 + f], acc);
        float y = acc + f1b[f];
        y = (y - bn1[128 + f]) * rsqrtf(bn1[192 + f] + EPSV) * bn1[f] + bn1[64 + f];
        Z1[g][f] = fmaxf(y, 0.0f);
    }
    __syncthreads();
    for (int o = t; o < 64 * 32; o += 256) {
        int g = o >> 5, f = o & 31;
        float acc = 0.0f;
        for (int c = 0; c < 64; ++c) acc = fmaf(Z1[g][c], f2W[c * 32 + f], acc);
        float y = acc + f2b[f];
        y = (y - bn2[64 + f]) * rsqrtf(bn2[96 + f] + EPSV) * bn2[f] + bn2[32 + f];
        Z2[g][f] = fmaxf(y, 0.0f);
    }
    __syncthreads();
    if (t < 64) {
        float acc = 0.0f;
        for (int c = 0; c < 32; ++c) acc = fmaf(Z2[t][c], f3W[c], acc);
        float y = acc + f3b[0];
        if (*cnt < 4) ((__hip_bfloat16*)out)[t] = __float2bfloat16(y);
        else          ((float*)out)[t] = y;
    }
}

extern "C" void kernel_launch(void* const* d_in, const int* in_sizes, int n_in,
                              void* d_out, int out_size, void* d_ws, size_t ws_size,
                              hipStream_t stream) {
    (void)in_sizes; (void)n_in; (void)out_size; (void)ws_size;
    const void* x     = d_in[0];
    const int*  eidx  = (const int*)d_in[1];
    const int*  batch = (const int*)d_in[2];

    const int n = NN, E = NE;
    const int* src = eidx;
    const int* dst = eidx + E;

    char* w = (char*)d_ws;
    // zero-init region (single memset): indeg8 | gcnt | pooled | cnt
    int*   indeg8 = (int*)w;  w += (size_t)8 * n * 4;
    int*   gcnt   = (int*)w;  w += 64 * 4;
    float* pooled = (float*)w; w += 64 * 128 * 4;
    int*   cnt    = (int*)w;  w += 16;
    size_t zbytes = (size_t)8 * n * 4 + 64 * 4 + 64 * 128 * 4 + 16;
    // rest
    unsigned short* hb = (unsigned short*)w; w += (size_t)n * 64 * 2;
    unsigned int* gb   = (unsigned int*)w;   w += (size_t)n * 64 * 4;
    unsigned int* C1b  = (unsigned int*)w;   w += (size_t)n * 64 * 4;
    unsigned int* C2b  = (unsigned int*)w;   w += (size_t)n * 64 * 4;
    unsigned short* C1f8 = (unsigned short*)w; w += (size_t)n * 64 * 2;
    unsigned char* hf8 = (unsigned char*)w;  w += (size_t)n * 64;
    int*   rowptr = (int*)w;  w += (size_t)(n + 8) * 4;
    int*   rank   = (int*)w;  w += (size_t)E * 4;
    int*   csr_src = (int*)w; w += (size_t)E * 4;
    float* dinv  = (float*)w; w += (size_t)n * 4;
    float* cinv  = (float*)w; w += (size_t)n * 4;
    int*   bsum  = (int*)w;  w += (NB + 8) * 4;
    int*   boff  = (int*)w;  w += (NB + 8) * 4;
    unsigned short* wt = (unsigned short*)w; w += (size_t)WT_TOT * 2;
    float* prm   = (float*)w;

    hipMemsetAsync(indeg8, 0, zbytes, stream);

    dim3 b256(256);

    const int DETN = 131072;
    k_detect<<<dim3(DETN / 256), b256, 0, stream>>>((const unsigned short*)x, cnt, DETN);

    PSrc ps;
    for (int i = 0; i < 17; ++i) ps.p[i] = d_in[3 + i];

    // fused front-end: degree | in_mfma | cvt | gcount (all mutually independent)
    k_front<<<dim3(NDEG + NGEMM + NCVT + NCOUNT), b256, 0, stream>>>(
        ps, cnt, dst, indeg8, rank, x, hb, hf8, prm, wt, batch, gcnt);

    // CSR finish
    k_scan1<<<dim3(NB), b256, 0, stream>>>(indeg8, rowptr, dinv, cinv, bsum, n);
    k_scan2<<<1, 64, 0, stream>>>(bsum, boff, rowptr, NB, n);
    k_fill<<<dim3((E + 1023) / 1024), b256, 0, stream>>>(src, dst, rowptr, boff, indeg8,
                                                          rank, csr_src, E);

    int gGemm = (n + 63) / 64;
    int gGath = (n + 3) / 4;
    int gPool = (n + 63) / 64;

    // layer 0 (fp8 gather operand; bf16 self)
    k_gather0<<<gGath, b256, 0, stream>>>(hf8, hb, dinv, cinv, rowptr, boff, csr_src, gb, n);
    k_layer_mfma<<<gGemm, b256, 0, stream>>>(gb, hb, 0,
        wt + 0, wt + 4096, wt + 8192,
        prm + PW_GCNB, prm + PW_SB, prm + PW_GCNBN, prm + PW_SBN, dinv, C1b, C1f8, n);

    // layer 1 (fp8 prescaled gather; bf16 self; bf16 output for pool)
    k_gather1<<<gGath, b256, 0, stream>>>(C1f8, C1b, dinv, cinv, rowptr, boff, csr_src, gb, n);
    k_layer_mfma<<<gGemm, b256, 0, stream>>>(gb, C1b, 1,
        wt + 12288, wt + 16384, wt + 20480,
        prm + PW_GCNB + 64, prm + PW_SB + 64, prm + PW_GCNBN + 256, prm + PW_SBN + 256,
        dinv, C2b, (unsigned short*)nullptr, n);

    // pooling + head
    k_pool2<<<gPool, b256, 0, stream>>>(C2b, batch, pooled, n);
    k_head<<<1, b256, 0, stream>>>(pooled, gcnt, prm, cnt, d_out);
}

// Round 15
// 353.062 us; speedup vs baseline: 1.0121x; 1.0121x over previous
//
#include <hip/hip_runtime.h>
#include <hip/hip_bf16.h>
#include <hip/hip_fp16.h>
#include <hip/hip_fp8.h>

#define NN 50000
#define NE 1200000
#define DIN 128
#define HDIM 64
#define NG 64
#define EPSV 1e-5f
#define SCANBLK 1024
#define NB ((NN + SCANBLK - 1) / SCANBLK)

typedef __attribute__((ext_vector_type(8))) short bfrag;   // 8 bf16 = 4 VGPRs
typedef __attribute__((ext_vector_type(4))) float ffrag;   // 4 fp32 acc

__device__ __forceinline__ float b2f(const __hip_bfloat16 v) { return __bfloat162float(v); }
__device__ __forceinline__ float bu2f(unsigned short u) {
    return __uint_as_float(((unsigned int)u) << 16);
}
__device__ __forceinline__ unsigned short f2bu(float f) {
    __hip_bfloat16 b = __float2bfloat16(f);
    return *(unsigned short*)&b;
}
__device__ __forceinline__ unsigned int packbf(float a, float b) {
    return (unsigned int)f2bu(a) | ((unsigned int)f2bu(b) << 16);
}
__device__ __forceinline__ unsigned int f2f8(float x) {
    __hip_fp8_e4m3 t(x);
    return (unsigned int)t.__x;
}
__device__ __forceinline__ float f82f(unsigned int b) {
    __hip_fp8_e4m3 t;
    t.__x = (__hip_fp8_storage_t)b;
    return (float)t;
}

__device__ __forceinline__ float ldf(const void* p, size_t idx, int isbf16) {
    return isbf16 ? b2f(((const __hip_bfloat16*)p)[idx]) : ((const float*)p)[idx];
}

__device__ __forceinline__ int xcc_id() {
    int x;
    asm volatile("s_getreg_b32 %0, hwreg(HW_REG_XCC_ID)" : "=s"(x));
    return x & 7;
}

// ---------------- dtype detection ----------------
__global__ void k_detect(const unsigned short* __restrict__ x, int* __restrict__ cnt, int n) {
    int i = blockIdx.x * 256 + threadIdx.x;
    if (i < n) {
        unsigned short u = x[i];
        if (((u >> 7) & 0xFF) == 0xFF) atomicAdd(cnt, 1);
    }
}

// ---------------- param offsets ----------------
#define PW_WIN   0
#define PW_BIN   8192
#define PW_GCNW  8256
#define PW_GCNB  16448
#define PW_GCNBN 16576
#define PW_SWL   17088
#define PW_SWR   25280
#define PW_SB    33472
#define PW_SBN   33600
#define PW_F1W   34112
#define PW_F1B   42304
#define PW_BN1   42368
#define PW_F2W   42624
#define PW_F2B   44672
#define PW_BN2   44704
#define PW_F3W   44832
#define PW_F3B   44864
#define PW_TOT   44865
#define WT_TOT   (6 * 4096)

// grid partition of k_front (interleaved: even bid -> degree, odd bid -> others)
#define NDEG   ((NE + 1023) / 1024)                 // 1172
#define NGEMM  ((NN + 63) / 64)                     // 782
#define NCVT   ((PW_TOT + WT_TOT + 255) / 256)      // 272
#define NCOUNT ((NN + 1023) / 1024)                 // 49
#define NOTHER (NGEMM + NCVT + NCOUNT)              // 1103
#define NFRONT (2 * NDEG)                           // 2344 (odd slots >= NOTHER idle)

struct PSrc { const void* p[17]; };

// ============ fused front-end: degree | in_mfma | cvt | gcount ============
// Even blocks = degree (atomic-latency-bound); odd blocks = compute parts.
// Round-robin dispatch co-locates both kinds on every CU from t=0, so the
// compute runs inside the atomic shadow (R14 failed because degree blocks
// occupied ALL resident slots first and nothing overlapped).
__global__ __launch_bounds__(256) void k_front(
        PSrc s, const int* __restrict__ cnt,
        const int* __restrict__ dst, int* __restrict__ indeg8, int* __restrict__ rank,
        const void* __restrict__ x, unsigned short* __restrict__ hb,
        unsigned char* __restrict__ hf8,
        float* __restrict__ prm, unsigned short* __restrict__ wt,
        const int* __restrict__ batch, int* __restrict__ gcnt) {
    __shared__ unsigned short smem[2 * 64 * 136];   // 34 KB union
    int t = threadIdx.x;

    if ((blockIdx.x & 1) == 0) {
        // ---- Part A: XCD-local degree counting ----
        int bid = blockIdx.x >> 1;
        int xc = xcc_id();
        int* my = indeg8 + (size_t)xc * NN;
        int hi = xc << 16;
        int e0 = (bid * 256 + t) * 4;
        if (e0 + 3 < NE) {
            int4 d = *(const int4*)&dst[e0];
            int r0 = atomicAdd(&my[d.x], 1);
            int r1 = atomicAdd(&my[d.y], 1);
            int r2 = atomicAdd(&my[d.z], 1);
            int r3 = atomicAdd(&my[d.w], 1);
            *(int4*)&rank[e0] = make_int4(hi | r0, hi | r1, hi | r2, hi | r3);
        } else {
            for (int e = e0; e < NE; ++e) rank[e] = hi | atomicAdd(&my[dst[e]], 1);
        }
        return;
    }
    int oid = blockIdx.x >> 1;   // odd blocks: other-part id
    if (oid >= NOTHER) return;

    if (oid < NGEMM) {
        // ---- Part B: input MFMA GEMM, self-loading W_in/b_in raw ----
        unsigned short (*Xs)[136] = (unsigned short (*)[136])smem;
        unsigned short (*Wt)[136] = (unsigned short (*)[136])(smem + 64 * 136);
        int v0 = oid * 64;
        int f16 = (*cnt < 4) ? 1 : 0;
        const void* xw = s.p[0];   // W_in raw [128][64]
#pragma unroll
        for (int j = 0; j < 32; ++j) {
            int i = t + 256 * j;
            int r = i >> 7, c = i & 127;
            int v = v0 + r;
            Xs[r][c] = (v < NN) ? f2bu(ldf(x, (size_t)v * DIN + c, f16)) : 0;
            // Wt[nn][kk] = W_in[kk][nn]
            Wt[i >> 7][i & 127] = f2bu(ldf(xw, (size_t)(i & 127) * 64 + (i >> 7), f16));
        }
        __syncthreads();
        int w = t >> 6, lane = t & 63;
        int m = lane & 15, kq = lane >> 4;
        int lr = w * 16 + m;
        bfrag a[4];
#pragma unroll
        for (int s2 = 0; s2 < 4; ++s2) a[s2] = *(const bfrag*)&Xs[lr][s2 * 32 + kq * 8];
        ffrag zf = {0.0f, 0.0f, 0.0f, 0.0f};
        ffrag acc[4] = {zf, zf, zf, zf};
#pragma unroll
        for (int nt = 0; nt < 4; ++nt)
#pragma unroll
            for (int s2 = 0; s2 < 4; ++s2) {
                bfrag b = *(const bfrag*)&Wt[nt * 16 + m][s2 * 32 + kq * 8];
                acc[nt] = __builtin_amdgcn_mfma_f32_16x16x32_bf16(a[s2], b, acc[nt], 0, 0, 0);
            }
#pragma unroll
        for (int nt = 0; nt < 4; ++nt) {
            int f = nt * 16 + m;
            float bb = ldf(s.p[1], f, f16);   // b_in raw
#pragma unroll
            for (int r = 0; r < 4; ++r) {
                int v = v0 + w * 16 + kq * 4 + r;
                if (v < NN) {
                    float y = fmaxf(acc[nt][r] + bb, 0.0f);
                    hb[(size_t)v * 64 + f] = f2bu(y);
                    hf8[(size_t)v * 64 + f] = (unsigned char)f2f8(y);
                }
            }
        }
    } else if (oid < NGEMM + NCVT) {
        // ---- Part D: param conversion + layer-weight transposes ----
        const int offs[18] = {PW_WIN, PW_BIN, PW_GCNW, PW_GCNB, PW_GCNBN, PW_SWL, PW_SWR,
                              PW_SB, PW_SBN, PW_F1W, PW_F1B, PW_BN1, PW_F2W, PW_F2B,
                              PW_BN2, PW_F3W, PW_F3B, PW_TOT};
        int i = (oid - NGEMM) * 256 + t;
        int f = (*cnt < 4) ? 1 : 0;
        if (i < PW_TOT) {
            int seg = 0;
            while (i >= offs[seg + 1]) ++seg;
            prm[i] = ldf(s.p[seg], i - offs[seg], f);
        } else if (i < PW_TOT + WT_TOT) {
            int j = i - PW_TOT;
            int mtx = j >> 12, idx = j & 4095;
            int nn = idx >> 6, kk = idx & 63;
            const void* wp = (mtx % 3 == 0) ? s.p[2] : (mtx % 3 == 1) ? s.p[5] : s.p[6];
            wt[j] = f2bu(ldf(wp, (size_t)(mtx / 3) * 4096 + kk * 64 + nn, f));
        }
    } else {
        // ---- Part C: graph-size histogram ----
        int* hist = (int*)smem;
        if (t < NG) hist[t] = 0;
        __syncthreads();
        int v = (oid - NGEMM - NCVT) * 1024 + t;
#pragma unroll
        for (int j = 0; j < 4; ++j, v += 256)
            if (v < NN) atomicAdd(&hist[batch[v]], 1);
        __syncthreads();
        if (t < NG) {
            int c = hist[t];
            if (c) atomicAdd(&gcnt[t], c);
        }
    }
}

// ---- scan1: sum 8 copies -> degree; overwrite copies with exclusive per-copy offsets ----
__global__ __launch_bounds__(256) void k_scan1(int* __restrict__ indeg8,
                                               int* __restrict__ rowptr,
                                               float* __restrict__ dinv,
                                               float* __restrict__ cinv,
                                               int* __restrict__ bsum, int n) {
    __shared__ int wsum[4];
    int t = threadIdx.x;
    int wid = t >> 6, lane = t & 63;
    int base = blockIdx.x * SCANBLK;
    int i0 = base + t * 4;
    int d[4];
#pragma unroll
    for (int j = 0; j < 4; ++j) {
        int i = i0 + j;
        int dsum = 0;
        if (i < n) {
            int run = 0;
#pragma unroll
            for (int c = 0; c < 8; ++c) {
                size_t o = (size_t)c * NN + i;
                int val = indeg8[o];
                indeg8[o] = run;
                run += val;
            }
            dsum = run;
            float fd = (float)dsum;
            dinv[i] = rsqrtf(fd + 1.0f);
            cinv[i] = 1.0f / fmaxf(fd, 1.0f);
        }
        d[j] = dsum;
    }
    int s = d[0] + d[1] + d[2] + d[3];
    int x = s;
#pragma unroll
    for (int off = 1; off < 64; off <<= 1) {
        int y = __shfl_up(x, off, 64);
        if (lane >= off) x += y;
    }
    if (lane == 63) wsum[wid] = x;
    __syncthreads();
    int woff = 0;
#pragma unroll
    for (int j = 0; j < 4; ++j) if (j < wid) woff += wsum[j];
    int excl = woff + x - s;
    int run = 0;
#pragma unroll
    for (int j = 0; j < 4; ++j) {
        int i = i0 + j;
        if (i < n) rowptr[i] = excl + run;
        run += d[j];
    }
    if (t == 0) bsum[blockIdx.x] = wsum[0] + wsum[1] + wsum[2] + wsum[3];
}

__global__ void k_scan2(const int* __restrict__ bsum, int* __restrict__ boff,
                        int* __restrict__ rowptr, int nb, int n) {
    int lane = threadIdx.x;
    int s = (lane < nb) ? bsum[lane] : 0;
    int x = s;
#pragma unroll
    for (int off = 1; off < 64; off <<= 1) {
        int y = __shfl_up(x, off, 64);
        if (lane >= off) x += y;
    }
    if (lane < nb) boff[lane] = x - s;
    if (lane == nb - 1) rowptr[n] = s;
}

__global__ __launch_bounds__(256) void k_fill(const int* __restrict__ src,
                                              const int* __restrict__ dst,
                                              const int* __restrict__ rowptr,
                                              const int* __restrict__ boff,
                                              const int* __restrict__ indeg8,
                                              const int* __restrict__ rank,
                                              int* __restrict__ csr_src, int E) {
    int e0 = (blockIdx.x * 256 + threadIdx.x) * 4;
    if (e0 + 3 < E) {
        int4 d = *(const int4*)&dst[e0];
        int4 r = *(const int4*)&rank[e0];
        int4 sc = *(const int4*)&src[e0];
        csr_src[rowptr[d.x] + boff[d.x >> 10] + indeg8[(size_t)(r.x >> 16) * NN + d.x]
                + (r.x & 0xFFFF)] = sc.x;
        csr_src[rowptr[d.y] + boff[d.y >> 10] + indeg8[(size_t)(r.y >> 16) * NN + d.y]
                + (r.y & 0xFFFF)] = sc.y;
        csr_src[rowptr[d.z] + boff[d.z >> 10] + indeg8[(size_t)(r.z >> 16) * NN + d.z]
                + (r.z & 0xFFFF)] = sc.z;
        csr_src[rowptr[d.w] + boff[d.w >> 10] + indeg8[(size_t)(r.w >> 16) * NN + d.w]
                + (r.w & 0xFFFF)] = sc.w;
    } else {
        for (int e = e0; e < E; ++e) {
            int d = dst[e];
            int r = rank[e];
            csr_src[rowptr[d] + boff[d >> 10] + indeg8[(size_t)(r >> 16) * NN + d]
                    + (r & 0xFFFF)] = src[e];
        }
    }
}

// ---------------- MFMA fused layer GEMM ----------------
__global__ __launch_bounds__(256) void k_layer_mfma(
        const unsigned int* __restrict__ gb, const void* __restrict__ selfp, int selfPacked,
        const unsigned short* __restrict__ W0t, const unsigned short* __restrict__ Wlt,
        const unsigned short* __restrict__ Wrt,
        const float* __restrict__ b0, const float* __restrict__ bs,
        const float* __restrict__ bn0, const float* __restrict__ bns,
        const float* __restrict__ dinv,
        unsigned int* __restrict__ outp, unsigned short* __restrict__ outf8, int n) {
    __shared__ unsigned int Ag[64][68];
    __shared__ unsigned int Su[64][68];
    __shared__ unsigned short Wt0[64][72];
    __shared__ unsigned short Wt1[64][72];
    int t = threadIdx.x;
    int v0 = blockIdx.x * 64;

    uint4 z4 = make_uint4(0, 0, 0, 0);
#pragma unroll
    for (int j = 0; j < 4; ++j) {
        int c = t + 256 * j;
        int r = c >> 4, cq = c & 15;
        int v = v0 + r;
        uint4 val = (v < n) ? *(const uint4*)&gb[(size_t)v * 64 + cq * 4] : z4;
        *(uint4*)&Ag[r][cq * 4] = val;
    }
    if (selfPacked) {
        const unsigned int* sp = (const unsigned int*)selfp;
#pragma unroll
        for (int j = 0; j < 4; ++j) {
            int c = t + 256 * j;
            int r = c >> 4, cq = c & 15;
            int v = v0 + r;
            uint4 val = (v < n) ? *(const uint4*)&sp[(size_t)v * 64 + cq * 4] : z4;
            *(uint4*)&Su[r][cq * 4] = val;
        }
    } else {
        const unsigned int* sp = (const unsigned int*)selfp;
#pragma unroll
        for (int j = 0; j < 2; ++j) {
            int c = t + 256 * j;
            int r = c >> 3, cq = c & 7;
            int v = v0 + r;
            uint4 val = (v < n) ? *(const uint4*)&sp[(size_t)v * 32 + cq * 4] : z4;
            *(uint4*)&Su[r][cq * 4] = val;
        }
    }
#pragma unroll
    for (int j = 0; j < 2; ++j) {
        int c = t + 256 * j;
        int r = c >> 3, cq = c & 7;
        *(uint4*)&Wt0[r][cq * 8] = *(const uint4*)&W0t[r * 64 + cq * 8];
        *(uint4*)&Wt1[r][cq * 8] = *(const uint4*)&Wlt[r * 64 + cq * 8];
    }
    __syncthreads();

    int w = t >> 6, lane = t & 63;
    int m = lane & 15, kq = lane >> 4;
    int lr = w * 16 + m;

    bfrag ag[2], as_[2], asl[2];
#pragma unroll
    for (int s = 0; s < 2; ++s) {
        uint4 u0 = *(const uint4*)&Ag[lr][s * 32 + kq * 8];
        uint4 u1 = *(const uint4*)&Ag[lr][s * 32 + kq * 8 + 4];
        unsigned int uu[8] = {u0.x, u0.y, u0.z, u0.w, u1.x, u1.y, u1.z, u1.w};
#pragma unroll
        for (int j = 0; j < 8; ++j) {
            ag[s][j] = (short)(uu[j] & 0xFFFF);
            as_[s][j] = (short)(uu[j] >> 16);
        }
        if (selfPacked) {
            uint4 s0 = *(const uint4*)&Su[lr][s * 32 + kq * 8];
            uint4 s1 = *(const uint4*)&Su[lr][s * 32 + kq * 8 + 4];
            unsigned int su[8] = {s0.x, s0.y, s0.z, s0.w, s1.x, s1.y, s1.z, s1.w};
#pragma unroll
            for (int j = 0; j < 8; ++j) asl[s][j] = (short)(su[j] >> 16);
        } else {
            const unsigned short* srow = (const unsigned short*)&Su[lr][0];
            asl[s] = *(const bfrag*)(srow + s * 32 + kq * 8);
        }
    }

    ffrag zf = {0.0f, 0.0f, 0.0f, 0.0f};
    ffrag accg[4] = {zf, zf, zf, zf};
    ffrag accs[4] = {zf, zf, zf, zf};
#pragma unroll
    for (int nt = 0; nt < 4; ++nt) {
#pragma unroll
        for (int s = 0; s < 2; ++s) {
            bfrag b0f = *(const bfrag*)&Wt0[nt * 16 + m][s * 32 + kq * 8];
            accg[nt] = __builtin_amdgcn_mfma_f32_16x16x32_bf16(ag[s], b0f, accg[nt], 0, 0, 0);
            bfrag b1f = *(const bfrag*)&Wt1[nt * 16 + m][s * 32 + kq * 8];
            accs[nt] = __builtin_amdgcn_mfma_f32_16x16x32_bf16(as_[s], b1f, accs[nt], 0, 0, 0);
        }
    }
    __syncthreads();
#pragma unroll
    for (int j = 0; j < 2; ++j) {
        int c = t + 256 * j;
        int r = c >> 3, cq = c & 7;
        *(uint4*)&Wt0[r][cq * 8] = *(const uint4*)&Wrt[r * 64 + cq * 8];
    }
    __syncthreads();
#pragma unroll
    for (int nt = 0; nt < 4; ++nt) {
#pragma unroll
        for (int s = 0; s < 2; ++s) {
            bfrag brf = *(const bfrag*)&Wt0[nt * 16 + m][s * 32 + kq * 8];
            accs[nt] = __builtin_amdgcn_mfma_f32_16x16x32_bf16(asl[s], brf, accs[nt], 0, 0, 0);
        }
    }
#pragma unroll
    for (int nt = 0; nt < 4; ++nt) {
        int f = nt * 16 + m;
        float bg = b0[f], bv = bs[f];
        float g0 = bn0[f], g1 = bn0[64 + f], g2 = bn0[128 + f];
        float g3 = rsqrtf(bn0[192 + f] + EPSV);
        float s0 = bns[f], s1 = bns[64 + f], s2 = bns[128 + f];
        float s3 = rsqrtf(bns[192 + f] + EPSV);
#pragma unroll
        for (int r = 0; r < 4; ++r) {
            int v = v0 + w * 16 + kq * 4 + r;
            if (v < n) {
                float yg = fmaxf((accg[nt][r] + bg - g2) * g3 * g0 + g1, 0.0f);
                float ys = fmaxf((accs[nt][r] + bv - s2) * s3 * s0 + s1, 0.0f);
                outp[(size_t)v * 64 + f] = packbf(yg, ys);
                if (outf8) {
                    float dv = dinv[v];
                    outf8[(size_t)v * 64 + f] =
                        (unsigned short)(f2f8(yg * dv) | (f2f8(ys) << 8));
                }
            }
        }
    }
}

// ------- quarter-wave dual gathers, fp8 operands -------
__global__ __launch_bounds__(256) void k_gather0(const unsigned char* __restrict__ hf8,
                                                 const unsigned short* __restrict__ hb,
                                                 const float* __restrict__ dinv,
                                                 const float* __restrict__ cinv,
                                                 const int* __restrict__ rowptr,
                                                 const int* __restrict__ boff,
                                                 const int* __restrict__ csr_src,
                                                 unsigned int* __restrict__ gb, int n) {
    int wid = threadIdx.x >> 6, lane = threadIdx.x & 63;
    int v = blockIdx.x * 4 + wid;
    if (v >= n) return;
    int q = lane >> 4, ql = lane & 15;
    int beg = rowptr[v] + boff[v >> 10];
    int end = rowptr[v + 1] + boff[(v + 1) >> 10];
    float accg[4] = {0, 0, 0, 0}, accs[4] = {0, 0, 0, 0};
    int i = beg;
    for (; i + 8 <= end; i += 8) {
        int s0 = csr_src[i + q];
        int s1 = csr_src[i + 4 + q];
        unsigned int u0 = *(const unsigned int*)&hf8[(size_t)s0 * 64 + ql * 4];
        unsigned int u1 = *(const unsigned int*)&hf8[(size_t)s1 * 64 + ql * 4];
        float w0 = dinv[s0], w1 = dinv[s1];
#pragma unroll
        for (int k = 0; k < 4; ++k) {
            float x0 = f82f((u0 >> (8 * k)) & 0xFF);
            float x1 = f82f((u1 >> (8 * k)) & 0xFF);
            accg[k] = fmaf(x0, w0, accg[k]); accs[k] += x0;
            accg[k] = fmaf(x1, w1, accg[k]); accs[k] += x1;
        }
    }
    for (; i < end; i += 4) {
        int e = i + q;
        if (e < end) {
            int s = csr_src[e];
            unsigned int u = *(const unsigned int*)&hf8[(size_t)s * 64 + ql * 4];
            float w = dinv[s];
#pragma unroll
            for (int k = 0; k < 4; ++k) {
                float x = f82f((u >> (8 * k)) & 0xFF);
                accg[k] = fmaf(x, w, accg[k]); accs[k] += x;
            }
        }
    }
#pragma unroll
    for (int k = 0; k < 4; ++k) {
        accg[k] += __shfl_xor(accg[k], 16, 64);
        accg[k] += __shfl_xor(accg[k], 32, 64);
        accs[k] += __shfl_xor(accs[k], 16, 64);
        accs[k] += __shfl_xor(accs[k], 32, 64);
    }
    if (q == 0) {
        float dv = dinv[v], cv = cinv[v];
        uint2 us = *(const uint2*)&hb[(size_t)v * 64 + ql * 4];
        float sx[4] = {bu2f((unsigned short)(us.x & 0xFFFF)), bu2f((unsigned short)(us.x >> 16)),
                       bu2f((unsigned short)(us.y & 0xFFFF)), bu2f((unsigned short)(us.y >> 16))};
        unsigned int pk[4];
#pragma unroll
        for (int k = 0; k < 4; ++k) {
            float yg = dv * (accg[k] + dv * sx[k]);
            float ys = cv * accs[k];
            pk[k] = packbf(yg, ys);
        }
        *(uint4*)&gb[(size_t)v * 64 + ql * 4] = make_uint4(pk[0], pk[1], pk[2], pk[3]);
    }
}

__global__ __launch_bounds__(256) void k_gather1(const unsigned short* __restrict__ Cf8,
                                                 const unsigned int* __restrict__ Cb,
                                                 const float* __restrict__ dinv,
                                                 const float* __restrict__ cinv,
                                                 const int* __restrict__ rowptr,
                                                 const int* __restrict__ boff,
                                                 const int* __restrict__ csr_src,
                                                 unsigned int* __restrict__ gb, int n) {
    int wid = threadIdx.x >> 6, lane = threadIdx.x & 63;
    int v = blockIdx.x * 4 + wid;
    if (v >= n) return;
    int q = lane >> 4, ql = lane & 15;
    int beg = rowptr[v] + boff[v >> 10];
    int end = rowptr[v + 1] + boff[(v + 1) >> 10];
    float accg[4] = {0, 0, 0, 0}, accs[4] = {0, 0, 0, 0};
    int i = beg;
    for (; i + 8 <= end; i += 8) {
        int s0 = csr_src[i + q];
        int s1 = csr_src[i + 4 + q];
        uint2 u0 = *(const uint2*)&Cf8[(size_t)s0 * 64 + ql * 4];
        uint2 u1 = *(const uint2*)&Cf8[(size_t)s1 * 64 + ql * 4];
        unsigned int p0[4] = {u0.x & 0xFFFF, u0.x >> 16, u0.y & 0xFFFF, u0.y >> 16};
        unsigned int p1[4] = {u1.x & 0xFFFF, u1.x >> 16, u1.y & 0xFFFF, u1.y >> 16};
#pragma unroll
        for (int k = 0; k < 4; ++k) {
            accg[k] += f82f(p0[k] & 0xFF) + f82f(p1[k] & 0xFF);
            accs[k] += f82f(p0[k] >> 8) + f82f(p1[k] >> 8);
        }
    }
    for (; i < end; i += 4) {
        int e = i + q;
        if (e < end) {
            int s = csr_src[e];
            uint2 u = *(const uint2*)&Cf8[(size_t)s * 64 + ql * 4];
            unsigned int p[4] = {u.x & 0xFFFF, u.x >> 16, u.y & 0xFFFF, u.y >> 16};
#pragma unroll
            for (int k = 0; k < 4; ++k) {
                accg[k] += f82f(p[k] & 0xFF);
                accs[k] += f82f(p[k] >> 8);
            }
        }
    }
#pragma unroll
    for (int k = 0; k < 4; ++k) {
        accg[k] += __shfl_xor(accg[k], 16, 64);
        accg[k] += __shfl_xor(accg[k], 32, 64);
        accs[k] += __shfl_xor(accs[k], 16, 64);
        accs[k] += __shfl_xor(accs[k], 32, 64);
    }
    if (q == 0) {
        float dv = dinv[v], cv = cinv[v];
        uint4 us = *(const uint4*)&Cb[(size_t)v * 64 + ql * 4];
        unsigned int su[4] = {us.x, us.y, us.z, us.w};
        unsigned int pk[4];
#pragma unroll
        for (int k = 0; k < 4; ++k) {
            float yg = dv * (accg[k] + dv * bu2f((unsigned short)(su[k] & 0xFFFF)));
            float ys = cv * accs[k];
            pk[k] = packbf(yg, ys);
        }
        *(uint4*)&gb[(size_t)v * 64 + ql * 4] = make_uint4(pk[0], pk[1], pk[2], pk[3]);
    }
}

// ---------------- pooling over packed bf16 final feats ----------------
__global__ __launch_bounds__(256) void k_pool2(const unsigned int* __restrict__ X2,
                                               const int* __restrict__ batch,
                                               float* __restrict__ pooled, int n) {
    int wid = threadIdx.x >> 6, lane = threadIdx.x & 63;
    int v0 = blockIdx.x * 64 + wid * 16;
    float ag = 0.0f, as = 0.0f;
    int g = -1;
    for (int j = 0; j < 16; ++j) {
        int v = v0 + j;
        if (v >= n) break;
        int b = batch[v];
        if (b != g) {
            if (g >= 0) {
                atomicAdd(&pooled[g * 128 + lane], ag);
                atomicAdd(&pooled[g * 128 + 64 + lane], as);
            }
            g = b; ag = 0.0f; as = 0.0f;
        }
        unsigned int u = X2[(size_t)v * 64 + lane];
        ag += bu2f((unsigned short)(u & 0xFFFF));
        as += bu2f((unsigned short)(u >> 16));
    }
    if (g >= 0) {
        atomicAdd(&pooled[g * 128 + lane], ag);
        atomicAdd(&pooled[g * 128 + 64 + lane], as);
    }
}

// ---------------- head MLP (single block) ----------------
__global__ __launch_bounds__(256) void k_head(const float* __restrict__ pooled,
                                              const int* __restrict__ gcnt,
                                              const float* __restrict__ P_,
                                              const int* __restrict__ cnt,
                                              void* __restrict__ out) {
    const float* f1W = P_ + PW_F1W;
    const float* f1b = P_ + PW_F1B;
    const float* bn1 = P_ + PW_BN1;
    const float* f2W = P_ + PW_F2W;
    const float* f2b = P_ + PW_F2B;
    const float* bn2 = P_ + PW_BN2;
    const float* f3W = P_ + PW_F3W;
    const float* f3b = P_ + PW_F3B;
    __shared__ float P[64][128];
    __shared__ float Z1[64][64];
    __shared__ float Z2[64][32];
    int t = threadIdx.x;
    for (int i = t; i < 64 * 128; i += 256) {
        int g = i >> 7;
        float c = fmaxf((float)gcnt[g], 1.0f);
        P[g][i & 127] = pooled[i] / c;
    }
    __syncthreads();
    for (int o = t; o < 64 * 64; o += 256) {
        int g = o >> 6, f = o & 63;
        float acc = 0.0f;
        for (int c = 0; c < 128; ++c) acc = fmaf(P[g][c], f1W[c * 64 + f], acc);
        float y = acc + f1b[f];
        y = (y - bn1[128 + f]) * rsqrtf(bn1[192 + f] + EPSV) * bn1[f] + bn1[64 + f];
        Z1[g][f] = fmaxf(y, 0.0f);
    }
    __syncthreads();
    for (int o = t; o < 64 * 32; o += 256) {
        int g = o >> 5, f = o & 31;
        float acc = 0.0f;
        for (int c = 0; c < 64; ++c) acc = fmaf(Z1[g][c], f2W[c * 32 + f], acc);
        float y = acc + f2b[f];
        y = (y - bn2[64 + f]) * rsqrtf(bn2[96 + f] + EPSV) * bn2[f] + bn2[32 + f];
        Z2[g][f] = fmaxf(y, 0.0f);
    }
    __syncthreads();
    if (t < 64) {
        float acc = 0.0f;
        for (int c = 0; c < 32; ++c) acc = fmaf(Z2[t][c], f3W[c], acc);
        float y = acc + f3b[0];
        if (*cnt < 4) ((__hip_bfloat16*)out)[t] = __float2bfloat16(y);
        else          ((float*)out)[t] = y;
    }
}

extern "C" void kernel_launch(void* const* d_in, const int* in_sizes, int n_in,
                              void* d_out, int out_size, void* d_ws, size_t ws_size,
                              hipStream_t stream) {
    (void)in_sizes; (void)n_in; (void)out_size; (void)ws_size;
    const void* x     = d_in[0];
    const int*  eidx  = (const int*)d_in[1];
    const int*  batch = (const int*)d_in[2];

    const int n = NN, E = NE;
    const int* src = eidx;
    const int* dst = eidx + E;

    char* w = (char*)d_ws;
    // zero-init region (single memset): indeg8 | gcnt | pooled | cnt
    int*   indeg8 = (int*)w;  w += (size_t)8 * n * 4;
    int*   gcnt   = (int*)w;  w += 64 * 4;
    float* pooled = (float*)w; w += 64 * 128 * 4;
    int*   cnt    = (int*)w;  w += 16;
    size_t zbytes = (size_t)8 * n * 4 + 64 * 4 + 64 * 128 * 4 + 16;
    // rest
    unsigned short* hb = (unsigned short*)w; w += (size_t)n * 64 * 2;
    unsigned int* gb   = (unsigned int*)w;   w += (size_t)n * 64 * 4;
    unsigned int* C1b  = (unsigned int*)w;   w += (size_t)n * 64 * 4;
    unsigned int* C2b  = (unsigned int*)w;   w += (size_t)n * 64 * 4;
    unsigned short* C1f8 = (unsigned short*)w; w += (size_t)n * 64 * 2;
    unsigned char* hf8 = (unsigned char*)w;  w += (size_t)n * 64;
    int*   rowptr = (int*)w;  w += (size_t)(n + 8) * 4;
    int*   rank   = (int*)w;  w += (size_t)E * 4;
    int*   csr_src = (int*)w; w += (size_t)E * 4;
    float* dinv  = (float*)w; w += (size_t)n * 4;
    float* cinv  = (float*)w; w += (size_t)n * 4;
    int*   bsum  = (int*)w;  w += (NB + 8) * 4;
    int*   boff  = (int*)w;  w += (NB + 8) * 4;
    unsigned short* wt = (unsigned short*)w; w += (size_t)WT_TOT * 2;
    float* prm   = (float*)w;

    hipMemsetAsync(indeg8, 0, zbytes, stream);

    dim3 b256(256);

    const int DETN = 131072;
    k_detect<<<dim3(DETN / 256), b256, 0, stream>>>((const unsigned short*)x, cnt, DETN);

    PSrc ps;
    for (int i = 0; i < 17; ++i) ps.p[i] = d_in[3 + i];

    // fused front-end, interleaved: even blocks degree, odd blocks compute
    k_front<<<dim3(NFRONT), b256, 0, stream>>>(
        ps, cnt, dst, indeg8, rank, x, hb, hf8, prm, wt, batch, gcnt);

    // CSR finish
    k_scan1<<<dim3(NB), b256, 0, stream>>>(indeg8, rowptr, dinv, cinv, bsum, n);
    k_scan2<<<1, 64, 0, stream>>>(bsum, boff, rowptr, NB, n);
    k_fill<<<dim3((E + 1023) / 1024), b256, 0, stream>>>(src, dst, rowptr, boff, indeg8,
                                                          rank, csr_src, E);

    int gGemm = (n + 63) / 64;
    int gGath = (n + 3) / 4;
    int gPool = (n + 63) / 64;

    // layer 0 (fp8 gather operand; bf16 self)
    k_gather0<<<gGath, b256, 0, stream>>>(hf8, hb, dinv, cinv, rowptr, boff, csr_src, gb, n);
    k_layer_mfma<<<gGemm, b256, 0, stream>>>(gb, hb, 0,
        wt + 0, wt + 4096, wt + 8192,
        prm + PW_GCNB, prm + PW_SB, prm + PW_GCNBN, prm + PW_SBN, dinv, C1b, C1f8, n);

    // layer 1 (fp8 prescaled gather; bf16 self; bf16 output for pool)
    k_gather1<<<gGath, b256, 0, stream>>>(C1f8, C1b, dinv, cinv, rowptr, boff, csr_src, gb, n);
    k_layer_mfma<<<gGemm, b256, 0, stream>>>(gb, C1b, 1,
        wt + 12288, wt + 16384, wt + 20480,
        prm + PW_GCNB + 64, prm + PW_SB + 64, prm + PW_GCNBN + 256, prm + PW_SBN + 256,
        dinv, C2b, (unsigned short*)nullptr, n);

    // pooling + head
    k_pool2<<<gPool, b256, 0, stream>>>(C2b, batch, pooled, n);
    k_head<<<1, b256, 0, stream>>>(pooled, gcnt, prm, cnt, d_out);
}

// Round 16
// 320.710 us; speedup vs baseline: 1.1142x; 1.1009x over previous
//
#include <hip/hip_runtime.h>
#include <hip/hip_bf16.h>
#include <hip/hip_fp16.h>
#include <hip/hip_fp8.h>

#define NN 50000
#define NE 1200000
#define DIN 128
#define HDIM 64
#define NG 64
#define EPSV 1e-5f

typedef __attribute__((ext_vector_type(8))) short bfrag;   // 8 bf16 = 4 VGPRs
typedef __attribute__((ext_vector_type(4))) float ffrag;   // 4 fp32 acc

__device__ __forceinline__ float b2f(const __hip_bfloat16 v) { return __bfloat162float(v); }
__device__ __forceinline__ float bu2f(unsigned short u) {
    return __uint_as_float(((unsigned int)u) << 16);
}
__device__ __forceinline__ unsigned short f2bu(float f) {
    __hip_bfloat16 b = __float2bfloat16(f);
    return *(unsigned short*)&b;
}
__device__ __forceinline__ unsigned int packbf(float a, float b) {
    return (unsigned int)f2bu(a) | ((unsigned int)f2bu(b) << 16);
}
__device__ __forceinline__ unsigned int f2f8(float x) {
    __hip_fp8_e4m3 t(x);
    return (unsigned int)t.__x;
}
__device__ __forceinline__ float f82f(unsigned int b) {
    __hip_fp8_e4m3 t;
    t.__x = (__hip_fp8_storage_t)b;
    return (float)t;
}

__device__ __forceinline__ float ldf(const void* p, size_t idx, int isbf16) {
    return isbf16 ? b2f(((const __hip_bfloat16*)p)[idx]) : ((const float*)p)[idx];
}

// ---------------- dtype detection ----------------
__global__ void k_detect(const unsigned short* __restrict__ x, int* __restrict__ cnt, int n) {
    int i = blockIdx.x * 256 + threadIdx.x;
    if (i < n) {
        unsigned short u = x[i];
        if (((u >> 7) & 0xFF) == 0xFF) atomicAdd(cnt, 1);
    }
}

// ---------------- param offsets ----------------
#define PW_WIN   0
#define PW_BIN   8192
#define PW_GCNW  8256
#define PW_GCNB  16448
#define PW_GCNBN 16576
#define PW_SWL   17088
#define PW_SWR   25280
#define PW_SB    33472
#define PW_SBN   33600
#define PW_F1W   34112
#define PW_F1B   42304
#define PW_BN1   42368
#define PW_F2W   42624
#define PW_F2B   44672
#define PW_BN2   44704
#define PW_F3W   44832
#define PW_F3B   44864
#define PW_TOT   44865
#define WT_TOT   (6 * 4096)

// counting-sort CSR parameters
#define NBUCK 196                      // coarse bucket = dst >> 8 (256 nodes/bucket)
#define EB    ((NE + 1023) / 1024)     // 1172 edge blocks, 1024 edges each

// k_front partition: in_mfma | cvt | gcount (no degree — sort-based CSR now)
#define NGEMM  ((NN + 63) / 64)                     // 782
#define NCVT   ((PW_TOT + WT_TOT + 255) / 256)      // 272
#define NCOUNT ((NN + 1023) / 1024)                 // 49
#define NOTHER (NGEMM + NCVT + NCOUNT)              // 1103

struct PSrc { const void* p[17]; };

// ============ fused front-end: in_mfma | cvt | gcount ============
__global__ __launch_bounds__(256) void k_front(
        PSrc s, const int* __restrict__ cnt,
        const void* __restrict__ x, unsigned short* __restrict__ hb,
        unsigned char* __restrict__ hf8,
        float* __restrict__ prm, unsigned short* __restrict__ wt,
        const int* __restrict__ batch, int* __restrict__ gcnt) {
    __shared__ unsigned short smem[2 * 64 * 136];   // 34 KB union
    int t = threadIdx.x;
    int oid = blockIdx.x;

    if (oid < NGEMM) {
        // ---- input MFMA GEMM, self-loading W_in/b_in raw ----
        unsigned short (*Xs)[136] = (unsigned short (*)[136])smem;
        unsigned short (*Wt)[136] = (unsigned short (*)[136])(smem + 64 * 136);
        int v0 = oid * 64;
        int f16 = (*cnt < 4) ? 1 : 0;
        const void* xw = s.p[0];   // W_in raw [128][64]
#pragma unroll
        for (int j = 0; j < 32; ++j) {
            int i = t + 256 * j;
            int r = i >> 7, c = i & 127;
            int v = v0 + r;
            Xs[r][c] = (v < NN) ? f2bu(ldf(x, (size_t)v * DIN + c, f16)) : 0;
            Wt[i >> 7][i & 127] = f2bu(ldf(xw, (size_t)(i & 127) * 64 + (i >> 7), f16));
        }
        __syncthreads();
        int w = t >> 6, lane = t & 63;
        int m = lane & 15, kq = lane >> 4;
        int lr = w * 16 + m;
        bfrag a[4];
#pragma unroll
        for (int s2 = 0; s2 < 4; ++s2) a[s2] = *(const bfrag*)&Xs[lr][s2 * 32 + kq * 8];
        ffrag zf = {0.0f, 0.0f, 0.0f, 0.0f};
        ffrag acc[4] = {zf, zf, zf, zf};
#pragma unroll
        for (int nt = 0; nt < 4; ++nt)
#pragma unroll
            for (int s2 = 0; s2 < 4; ++s2) {
                bfrag b = *(const bfrag*)&Wt[nt * 16 + m][s2 * 32 + kq * 8];
                acc[nt] = __builtin_amdgcn_mfma_f32_16x16x32_bf16(a[s2], b, acc[nt], 0, 0, 0);
            }
#pragma unroll
        for (int nt = 0; nt < 4; ++nt) {
            int f = nt * 16 + m;
            float bb = ldf(s.p[1], f, f16);
#pragma unroll
            for (int r = 0; r < 4; ++r) {
                int v = v0 + w * 16 + kq * 4 + r;
                if (v < NN) {
                    float y = fmaxf(acc[nt][r] + bb, 0.0f);
                    hb[(size_t)v * 64 + f] = f2bu(y);
                    hf8[(size_t)v * 64 + f] = (unsigned char)f2f8(y);
                }
            }
        }
    } else if (oid < NGEMM + NCVT) {
        // ---- param conversion + layer-weight transposes ----
        const int offs[18] = {PW_WIN, PW_BIN, PW_GCNW, PW_GCNB, PW_GCNBN, PW_SWL, PW_SWR,
                              PW_SB, PW_SBN, PW_F1W, PW_F1B, PW_BN1, PW_F2W, PW_F2B,
                              PW_BN2, PW_F3W, PW_F3B, PW_TOT};
        int i = (oid - NGEMM) * 256 + t;
        int f = (*cnt < 4) ? 1 : 0;
        if (i < PW_TOT) {
            int seg = 0;
            while (i >= offs[seg + 1]) ++seg;
            prm[i] = ldf(s.p[seg], i - offs[seg], f);
        } else if (i < PW_TOT + WT_TOT) {
            int j = i - PW_TOT;
            int mtx = j >> 12, idx = j & 4095;
            int nn = idx >> 6, kk = idx & 63;
            const void* wp = (mtx % 3 == 0) ? s.p[2] : (mtx % 3 == 1) ? s.p[5] : s.p[6];
            wt[j] = f2bu(ldf(wp, (size_t)(mtx / 3) * 4096 + kk * 64 + nn, f));
        }
    } else {
        // ---- graph-size histogram ----
        int* hist = (int*)smem;
        if (t < NG) hist[t] = 0;
        __syncthreads();
        int v = (oid - NGEMM - NCVT) * 1024 + t;
#pragma unroll
        for (int j = 0; j < 4; ++j, v += 256)
            if (v < NN) atomicAdd(&hist[batch[v]], 1);
        __syncthreads();
        if (t < NG) {
            int c = hist[t];
            if (c) atomicAdd(&gcnt[t], c);
        }
    }
}

// ========== counting-sort CSR build (no global atomics) ==========
// Pass 1: per-block LDS histogram over coarse buckets; counts[bucket][block].
__global__ __launch_bounds__(256) void k_hist(const int* __restrict__ dst,
                                              int* __restrict__ counts, int E) {
    __shared__ int hist[NBUCK];
    int t = threadIdx.x, bid = blockIdx.x;
    if (t < NBUCK) hist[t] = 0;
    __syncthreads();
    int e0 = bid * 1024 + t * 4;
    if (e0 + 3 < E) {
        int4 d = *(const int4*)&dst[e0];
        atomicAdd(&hist[d.x >> 8], 1);
        atomicAdd(&hist[d.y >> 8], 1);
        atomicAdd(&hist[d.z >> 8], 1);
        atomicAdd(&hist[d.w >> 8], 1);
    } else {
        for (int e = e0; e < E && e < e0 + 4; ++e) atomicAdd(&hist[dst[e] >> 8], 1);
    }
    __syncthreads();
    if (t < NBUCK) counts[(size_t)t * EB + bid] = hist[t];
}

// Pass 2a: per-bucket exclusive scan of its EB block counts (in place); bucktot[b].
__global__ __launch_bounds__(256) void k_scanA(int* __restrict__ counts,
                                               int* __restrict__ bucktot) {
    __shared__ int ws[4];
    __shared__ int carry_s;
    int b = blockIdx.x, t = threadIdx.x;
    int wid = t >> 6, lane = t & 63;
    int* row = counts + (size_t)b * EB;
    if (t == 0) carry_s = 0;
    __syncthreads();
    for (int base = 0; base < EB; base += 1024) {
        int i0 = base + t * 4;
        int d[4];
#pragma unroll
        for (int j = 0; j < 4; ++j) d[j] = (i0 + j < EB) ? row[i0 + j] : 0;
        int s = d[0] + d[1] + d[2] + d[3];
        int x = s;
#pragma unroll
        for (int off = 1; off < 64; off <<= 1) {
            int y = __shfl_up(x, off, 64);
            if (lane >= off) x += y;
        }
        if (lane == 63) ws[wid] = x;
        __syncthreads();
        int woff = 0;
#pragma unroll
        for (int j = 0; j < 4; ++j) if (j < wid) woff += ws[j];
        int carry = carry_s;
        int excl = carry + woff + x - s;
        int run = 0;
#pragma unroll
        for (int j = 0; j < 4; ++j) {
            if (i0 + j < EB) row[i0 + j] = excl + run;
            run += d[j];
        }
        __syncthreads();
        if (t == 255) carry_s = carry + ws[0] + ws[1] + ws[2] + ws[3];
        __syncthreads();
    }
    if (t == 0) bucktot[b] = carry_s;
}

// Pass 2b: exclusive scan of bucket totals -> buckBase; rowptr[NN] = E.
__global__ __launch_bounds__(256) void k_scanB(const int* __restrict__ bucktot,
                                               int* __restrict__ buckBase,
                                               int* __restrict__ rowptr) {
    __shared__ int buf[256];
    int t = threadIdx.x;
    int v0 = (t < NBUCK) ? bucktot[t] : 0;
    buf[t] = v0;
    __syncthreads();
    for (int off = 1; off < 256; off <<= 1) {
        int v = (t >= off) ? buf[t - off] : 0;
        __syncthreads();
        buf[t] += v;
        __syncthreads();
    }
    if (t < NBUCK) buckBase[t] = buf[t] - v0;
    if (t == NBUCK - 1) {
        buckBase[NBUCK] = buf[t];
        rowptr[NN] = buf[t];     // == E
    }
}

// Pass 3: scatter (dst,src) pairs into bucket-sorted order; LDS-atomic ranks only.
__global__ __launch_bounds__(256) void k_scatter(const int* __restrict__ src,
                                                 const int* __restrict__ dst,
                                                 const int* __restrict__ counts,
                                                 const int* __restrict__ buckBase,
                                                 int2* __restrict__ pairs, int E) {
    __shared__ int hist[NBUCK];
    __shared__ int base_s[NBUCK];
    int t = threadIdx.x, bid = blockIdx.x;
    if (t < NBUCK) {
        hist[t] = 0;
        base_s[t] = buckBase[t] + counts[(size_t)t * EB + bid];
    }
    __syncthreads();
    int e0 = bid * 1024 + t * 4;
#pragma unroll
    for (int j = 0; j < 4; ++j) {
        int e = e0 + j;
        if (e < E) {
            int d = dst[e];
            int b = d >> 8;
            int r = atomicAdd(&hist[b], 1);
            pairs[base_s[b] + r] = make_int2(d, src[e]);
        }
    }
}

// Pass 4: per-bucket fine CSR: degrees, rowptr, dinv/cinv, final csr_src.
__global__ __launch_bounds__(256) void k_bucket(const int2* __restrict__ pairs,
                                                const int* __restrict__ buckBase,
                                                int* __restrict__ rowptr,
                                                float* __restrict__ dinv,
                                                float* __restrict__ cinv,
                                                int* __restrict__ csr_src, int n) {
    __shared__ int fine[256];
    __shared__ int foff[256];
    __shared__ int h2[256];
    __shared__ int ws[4];
    int b = blockIdx.x, t = threadIdx.x;
    int base = b << 8;
    int ebeg = buckBase[b], eend = buckBase[b + 1];
    fine[t] = 0;
    h2[t] = 0;
    __syncthreads();
    for (int e = ebeg + t; e < eend; e += 256) atomicAdd(&fine[pairs[e].x - base], 1);
    __syncthreads();
    // exclusive scan of fine[256]
    int wid = t >> 6, lane = t & 63;
    int d = fine[t];
    int x = d;
#pragma unroll
    for (int off = 1; off < 64; off <<= 1) {
        int y = __shfl_up(x, off, 64);
        if (lane >= off) x += y;
    }
    if (lane == 63) ws[wid] = x;
    __syncthreads();
    int woff = 0;
#pragma unroll
    for (int j = 0; j < 4; ++j) if (j < wid) woff += ws[j];
    foff[t] = woff + x - d;   // exclusive within bucket
    __syncthreads();
    int node = base + t;
    if (node < n) {
        rowptr[node] = ebeg + foff[t];
        float fd = (float)d;
        dinv[node] = rsqrtf(fd + 1.0f);
        cinv[node] = 1.0f / fmaxf(fd, 1.0f);
    }
    for (int e = ebeg + t; e < eend; e += 256) {
        int2 p = pairs[e];
        int li = p.x - base;
        int r = atomicAdd(&h2[li], 1);
        csr_src[ebeg + foff[li] + r] = p.y;
    }
}

// ---------------- MFMA fused layer GEMM ----------------
__global__ __launch_bounds__(256) void k_layer_mfma(
        const unsigned int* __restrict__ gb, const void* __restrict__ selfp, int selfPacked,
        const unsigned short* __restrict__ W0t, const unsigned short* __restrict__ Wlt,
        const unsigned short* __restrict__ Wrt,
        const float* __restrict__ b0, const float* __restrict__ bs,
        const float* __restrict__ bn0, const float* __restrict__ bns,
        const float* __restrict__ dinv,
        unsigned int* __restrict__ outp, unsigned short* __restrict__ outf8, int n) {
    __shared__ unsigned int Ag[64][68];
    __shared__ unsigned int Su[64][68];
    __shared__ unsigned short Wt0[64][72];
    __shared__ unsigned short Wt1[64][72];
    int t = threadIdx.x;
    int v0 = blockIdx.x * 64;

    uint4 z4 = make_uint4(0, 0, 0, 0);
#pragma unroll
    for (int j = 0; j < 4; ++j) {
        int c = t + 256 * j;
        int r = c >> 4, cq = c & 15;
        int v = v0 + r;
        uint4 val = (v < n) ? *(const uint4*)&gb[(size_t)v * 64 + cq * 4] : z4;
        *(uint4*)&Ag[r][cq * 4] = val;
    }
    if (selfPacked) {
        const unsigned int* sp = (const unsigned int*)selfp;
#pragma unroll
        for (int j = 0; j < 4; ++j) {
            int c = t + 256 * j;
            int r = c >> 4, cq = c & 15;
            int v = v0 + r;
            uint4 val = (v < n) ? *(const uint4*)&sp[(size_t)v * 64 + cq * 4] : z4;
            *(uint4*)&Su[r][cq * 4] = val;
        }
    } else {
        const unsigned int* sp = (const unsigned int*)selfp;
#pragma unroll
        for (int j = 0; j < 2; ++j) {
            int c = t + 256 * j;
            int r = c >> 3, cq = c & 7;
            int v = v0 + r;
            uint4 val = (v < n) ? *(const uint4*)&sp[(size_t)v * 32 + cq * 4] : z4;
            *(uint4*)&Su[r][cq * 4] = val;
        }
    }
#pragma unroll
    for (int j = 0; j < 2; ++j) {
        int c = t + 256 * j;
        int r = c >> 3, cq = c & 7;
        *(uint4*)&Wt0[r][cq * 8] = *(const uint4*)&W0t[r * 64 + cq * 8];
        *(uint4*)&Wt1[r][cq * 8] = *(const uint4*)&Wlt[r * 64 + cq * 8];
    }
    __syncthreads();

    int w = t >> 6, lane = t & 63;
    int m = lane & 15, kq = lane >> 4;
    int lr = w * 16 + m;

    bfrag ag[2], as_[2], asl[2];
#pragma unroll
    for (int s = 0; s < 2; ++s) {
        uint4 u0 = *(const uint4*)&Ag[lr][s * 32 + kq * 8];
        uint4 u1 = *(const uint4*)&Ag[lr][s * 32 + kq * 8 + 4];
        unsigned int uu[8] = {u0.x, u0.y, u0.z, u0.w, u1.x, u1.y, u1.z, u1.w};
#pragma unroll
        for (int j = 0; j < 8; ++j) {
            ag[s][j] = (short)(uu[j] & 0xFFFF);
            as_[s][j] = (short)(uu[j] >> 16);
        }
        if (selfPacked) {
            uint4 s0 = *(const uint4*)&Su[lr][s * 32 + kq * 8];
            uint4 s1 = *(const uint4*)&Su[lr][s * 32 + kq * 8 + 4];
            unsigned int su[8] = {s0.x, s0.y, s0.z, s0.w, s1.x, s1.y, s1.z, s1.w};
#pragma unroll
            for (int j = 0; j < 8; ++j) asl[s][j] = (short)(su[j] >> 16);
        } else {
            const unsigned short* srow = (const unsigned short*)&Su[lr][0];
            asl[s] = *(const bfrag*)(srow + s * 32 + kq * 8);
        }
    }

    ffrag zf = {0.0f, 0.0f, 0.0f, 0.0f};
    ffrag accg[4] = {zf, zf, zf, zf};
    ffrag accs[4] = {zf, zf, zf, zf};
#pragma unroll
    for (int nt = 0; nt < 4; ++nt) {
#pragma unroll
        for (int s = 0; s < 2; ++s) {
            bfrag b0f = *(const bfrag*)&Wt0[nt * 16 + m][s * 32 + kq * 8];
            accg[nt] = __builtin_amdgcn_mfma_f32_16x16x32_bf16(ag[s], b0f, accg[nt], 0, 0, 0);
            bfrag b1f = *(const bfrag*)&Wt1[nt * 16 + m][s * 32 + kq * 8];
            accs[nt] = __builtin_amdgcn_mfma_f32_16x16x32_bf16(as_[s], b1f, accs[nt], 0, 0, 0);
        }
    }
    __syncthreads();
#pragma unroll
    for (int j = 0; j < 2; ++j) {
        int c = t + 256 * j;
        int r = c >> 3, cq = c & 7;
        *(uint4*)&Wt0[r][cq * 8] = *(const uint4*)&Wrt[r * 64 + cq * 8];
    }
    __syncthreads();
#pragma unroll
    for (int nt = 0; nt < 4; ++nt) {
#pragma unroll
        for (int s = 0; s < 2; ++s) {
            bfrag brf = *(const bfrag*)&Wt0[nt * 16 + m][s * 32 + kq * 8];
            accs[nt] = __builtin_amdgcn_mfma_f32_16x16x32_bf16(asl[s], brf, accs[nt], 0, 0, 0);
        }
    }
#pragma unroll
    for (int nt = 0; nt < 4; ++nt) {
        int f = nt * 16 + m;
        float bg = b0[f], bv = bs[f];
        float g0 = bn0[f], g1 = bn0[64 + f], g2 = bn0[128 + f];
        float g3 = rsqrtf(bn0[192 + f] + EPSV);
        float s0 = bns[f], s1 = bns[64 + f], s2 = bns[128 + f];
        float s3 = rsqrtf(bns[192 + f] + EPSV);
#pragma unroll
        for (int r = 0; r < 4; ++r) {
            int v = v0 + w * 16 + kq * 4 + r;
            if (v < n) {
                float yg = fmaxf((accg[nt][r] + bg - g2) * g3 * g0 + g1, 0.0f);
                float ys = fmaxf((accs[nt][r] + bv - s2) * s3 * s0 + s1, 0.0f);
                outp[(size_t)v * 64 + f] = packbf(yg, ys);
                if (outf8) {
                    float dv = dinv[v];
                    outf8[(size_t)v * 64 + f] =
                        (unsigned short)(f2f8(yg * dv) | (f2f8(ys) << 8));
                }
            }
        }
    }
}

// ------- quarter-wave dual gathers, fp8 operands -------
__global__ __launch_bounds__(256) void k_gather0(const unsigned char* __restrict__ hf8,
                                                 const unsigned short* __restrict__ hb,
                                                 const float* __restrict__ dinv,
                                                 const float* __restrict__ cinv,
                                                 const int* __restrict__ rowptr,
                                                 const int* __restrict__ csr_src,
                                                 unsigned int* __restrict__ gb, int n) {
    int wid = threadIdx.x >> 6, lane = threadIdx.x & 63;
    int v = blockIdx.x * 4 + wid;
    if (v >= n) return;
    int q = lane >> 4, ql = lane & 15;
    int beg = rowptr[v], end = rowptr[v + 1];
    float accg[4] = {0, 0, 0, 0}, accs[4] = {0, 0, 0, 0};
    int i = beg;
    for (; i + 8 <= end; i += 8) {
        int s0 = csr_src[i + q];
        int s1 = csr_src[i + 4 + q];
        unsigned int u0 = *(const unsigned int*)&hf8[(size_t)s0 * 64 + ql * 4];
        unsigned int u1 = *(const unsigned int*)&hf8[(size_t)s1 * 64 + ql * 4];
        float w0 = dinv[s0], w1 = dinv[s1];
#pragma unroll
        for (int k = 0; k < 4; ++k) {
            float x0 = f82f((u0 >> (8 * k)) & 0xFF);
            float x1 = f82f((u1 >> (8 * k)) & 0xFF);
            accg[k] = fmaf(x0, w0, accg[k]); accs[k] += x0;
            accg[k] = fmaf(x1, w1, accg[k]); accs[k] += x1;
        }
    }
    for (; i < end; i += 4) {
        int e = i + q;
        if (e < end) {
            int s = csr_src[e];
            unsigned int u = *(const unsigned int*)&hf8[(size_t)s * 64 + ql * 4];
            float w = dinv[s];
#pragma unroll
            for (int k = 0; k < 4; ++k) {
                float x = f82f((u >> (8 * k)) & 0xFF);
                accg[k] = fmaf(x, w, accg[k]); accs[k] += x;
            }
        }
    }
#pragma unroll
    for (int k = 0; k < 4; ++k) {
        accg[k] += __shfl_xor(accg[k], 16, 64);
        accg[k] += __shfl_xor(accg[k], 32, 64);
        accs[k] += __shfl_xor(accs[k], 16, 64);
        accs[k] += __shfl_xor(accs[k], 32, 64);
    }
    if (q == 0) {
        float dv = dinv[v], cv = cinv[v];
        uint2 us = *(const uint2*)&hb[(size_t)v * 64 + ql * 4];
        float sx[4] = {bu2f((unsigned short)(us.x & 0xFFFF)), bu2f((unsigned short)(us.x >> 16)),
                       bu2f((unsigned short)(us.y & 0xFFFF)), bu2f((unsigned short)(us.y >> 16))};
        unsigned int pk[4];
#pragma unroll
        for (int k = 0; k < 4; ++k) {
            float yg = dv * (accg[k] + dv * sx[k]);
            float ys = cv * accs[k];
            pk[k] = packbf(yg, ys);
        }
        *(uint4*)&gb[(size_t)v * 64 + ql * 4] = make_uint4(pk[0], pk[1], pk[2], pk[3]);
    }
}

__global__ __launch_bounds__(256) void k_gather1(const unsigned short* __restrict__ Cf8,
                                                 const unsigned int* __restrict__ Cb,
                                                 const float* __restrict__ dinv,
                                                 const float* __restrict__ cinv,
                                                 const int* __restrict__ rowptr,
                                                 const int* __restrict__ csr_src,
                                                 unsigned int* __restrict__ gb, int n) {
    int wid = threadIdx.x >> 6, lane = threadIdx.x & 63;
    int v = blockIdx.x * 4 + wid;
    if (v >= n) return;
    int q = lane >> 4, ql = lane & 15;
    int beg = rowptr[v], end = rowptr[v + 1];
    float accg[4] = {0, 0, 0, 0}, accs[4] = {0, 0, 0, 0};
    int i = beg;
    for (; i + 8 <= end; i += 8) {
        int s0 = csr_src[i + q];
        int s1 = csr_src[i + 4 + q];
        uint2 u0 = *(const uint2*)&Cf8[(size_t)s0 * 64 + ql * 4];
        uint2 u1 = *(const uint2*)&Cf8[(size_t)s1 * 64 + ql * 4];
        unsigned int p0[4] = {u0.x & 0xFFFF, u0.x >> 16, u0.y & 0xFFFF, u0.y >> 16};
        unsigned int p1[4] = {u1.x & 0xFFFF, u1.x >> 16, u1.y & 0xFFFF, u1.y >> 16};
#pragma unroll
        for (int k = 0; k < 4; ++k) {
            accg[k] += f82f(p0[k] & 0xFF) + f82f(p1[k] & 0xFF);
            accs[k] += f82f(p0[k] >> 8) + f82f(p1[k] >> 8);
        }
    }
    for (; i < end; i += 4) {
        int e = i + q;
        if (e < end) {
            int s = csr_src[e];
            uint2 u = *(const uint2*)&Cf8[(size_t)s * 64 + ql * 4];
            unsigned int p[4] = {u.x & 0xFFFF, u.x >> 16, u.y & 0xFFFF, u.y >> 16};
#pragma unroll
            for (int k = 0; k < 4; ++k) {
                accg[k] += f82f(p[k] & 0xFF);
                accs[k] += f82f(p[k] >> 8);
            }
        }
    }
#pragma unroll
    for (int k = 0; k < 4; ++k) {
        accg[k] += __shfl_xor(accg[k], 16, 64);
        accg[k] += __shfl_xor(accg[k], 32, 64);
        accs[k] += __shfl_xor(accs[k], 16, 64);
        accs[k] += __shfl_xor(accs[k], 32, 64);
    }
    if (q == 0) {
        float dv = dinv[v], cv = cinv[v];
        uint4 us = *(const uint4*)&Cb[(size_t)v * 64 + ql * 4];
        unsigned int su[4] = {us.x, us.y, us.z, us.w};
        unsigned int pk[4];
#pragma unroll
        for (int k = 0; k < 4; ++k) {
            float yg = dv * (accg[k] + dv * bu2f((unsigned short)(su[k] & 0xFFFF)));
            float ys = cv * accs[k];
            pk[k] = packbf(yg, ys);
        }
        *(uint4*)&gb[(size_t)v * 64 + ql * 4] = make_uint4(pk[0], pk[1], pk[2], pk[3]);
    }
}

// ---------------- pooling over packed bf16 final feats ----------------
__global__ __launch_bounds__(256) void k_pool2(const unsigned int* __restrict__ X2,
                                               const int* __restrict__ batch,
                                               float* __restrict__ pooled, int n) {
    int wid = threadIdx.x >> 6, lane = threadIdx.x & 63;
    int v0 = blockIdx.x * 64 + wid * 16;
    float ag = 0.0f, as = 0.0f;
    int g = -1;
    for (int j = 0; j < 16; ++j) {
        int v = v0 + j;
        if (v >= n) break;
        int b = batch[v];
        if (b != g) {
            if (g >= 0) {
                atomicAdd(&pooled[g * 128 + lane], ag);
                atomicAdd(&pooled[g * 128 + 64 + lane], as);
            }
            g = b; ag = 0.0f; as = 0.0f;
        }
        unsigned int u = X2[(size_t)v * 64 + lane];
        ag += bu2f((unsigned short)(u & 0xFFFF));
        as += bu2f((unsigned short)(u >> 16));
    }
    if (g >= 0) {
        atomicAdd(&pooled[g * 128 + lane], ag);
        atomicAdd(&pooled[g * 128 + 64 + lane], as);
    }
}

// ---------------- head MLP (single block) ----------------
__global__ __launch_bounds__(256) void k_head(const float* __restrict__ pooled,
                                              const int* __restrict__ gcnt,
                                              const float* __restrict__ P_,
                                              const int* __restrict__ cnt,
                                              void* __restrict__ out) {
    const float* f1W = P_ + PW_F1W;
    const float* f1b = P_ + PW_F1B;
    const float* bn1 = P_ + PW_BN1;
    const float* f2W = P_ + PW_F2W;
    const float* f2b = P_ + PW_F2B;
    const float* bn2 = P_ + PW_BN2;
    const float* f3W = P_ + PW_F3W;
    const float* f3b = P_ + PW_F3B;
    __shared__ float P[64][128];
    __shared__ float Z1[64][64];
    __shared__ float Z2[64][32];
    int t = threadIdx.x;
    for (int i = t; i < 64 * 128; i += 256) {
        int g = i >> 7;
        float c = fmaxf((float)gcnt[g], 1.0f);
        P[g][i & 127] = pooled[i] / c;
    }
    __syncthreads();
    for (int o = t; o < 64 * 64; o += 256) {
        int g = o >> 6, f = o & 63;
        float acc = 0.0f;
        for (int c = 0; c < 128; ++c) acc = fmaf(P[g][c], f1W[c * 64 + f], acc);
        float y = acc + f1b[f];
        y = (y - bn1[128 + f]) * rsqrtf(bn1[192 + f] + EPSV) * bn1[f] + bn1[64 + f];
        Z1[g][f] = fmaxf(y, 0.0f);
    }
    __syncthreads();
    for (int o = t; o < 64 * 32; o += 256) {
        int g = o >> 5, f = o & 31;
        float acc = 0.0f;
        for (int c = 0; c < 64; ++c) acc = fmaf(Z1[g][c], f2W[c * 32 + f], acc);
        float y = acc + f2b[f];
        y = (y - bn2[64 + f]) * rsqrtf(bn2[96 + f] + EPSV) * bn2[f] + bn2[32 + f];
        Z2[g][f] = fmaxf(y, 0.0f);
    }
    __syncthreads();
    if (t < 64) {
        float acc = 0.0f;
        for (int c = 0; c < 32; ++c) acc = fmaf(Z2[t][c], f3W[c], acc);
        float y = acc + f3b[0];
        if (*cnt < 4) ((__hip_bfloat16*)out)[t] = __float2bfloat16(y);
        else          ((float*)out)[t] = y;
    }
}

extern "C" void kernel_launch(void* const* d_in, const int* in_sizes, int n_in,
                              void* d_out, int out_size, void* d_ws, size_t ws_size,
                              hipStream_t stream) {
    (void)in_sizes; (void)n_in; (void)out_size; (void)ws_size;
    const void* x     = d_in[0];
    const int*  eidx  = (const int*)d_in[1];
    const int*  batch = (const int*)d_in[2];

    const int n = NN, E = NE;
    const int* src = eidx;
    const int* dst = eidx + E;

    char* w = (char*)d_ws;
    // zero-init region (single small memset): gcnt | pooled | cnt
    int*   gcnt   = (int*)w;  w += 64 * 4;
    float* pooled = (float*)w; w += 64 * 128 * 4;
    int*   cnt    = (int*)w;  w += 16;
    size_t zbytes = 64 * 4 + 64 * 128 * 4 + 16;
    // rest
    unsigned short* hb = (unsigned short*)w; w += (size_t)n * 64 * 2;
    unsigned int* gb   = (unsigned int*)w;   w += (size_t)n * 64 * 4;
    unsigned int* C1b  = (unsigned int*)w;   w += (size_t)n * 64 * 4;
    unsigned int* C2b  = (unsigned int*)w;   w += (size_t)n * 64 * 4;
    unsigned short* C1f8 = (unsigned short*)w; w += (size_t)n * 64 * 2;
    unsigned char* hf8 = (unsigned char*)w;  w += (size_t)n * 64;
    int*   rowptr = (int*)w;  w += (size_t)(n + 8) * 4;
    int*   counts = (int*)w;  w += (size_t)NBUCK * EB * 4;
    int*   bucktot = (int*)w; w += (NBUCK + 8) * 4;
    int*   buckBase = (int*)w; w += (NBUCK + 8) * 4;
    int2*  pairs  = (int2*)w; w += (size_t)E * 8;
    int*   csr_src = (int*)w; w += (size_t)E * 4;
    float* dinv  = (float*)w; w += (size_t)n * 4;
    float* cinv  = (float*)w; w += (size_t)n * 4;
    unsigned short* wt = (unsigned short*)w; w += (size_t)WT_TOT * 2;
    float* prm   = (float*)w;

    hipMemsetAsync(gcnt, 0, zbytes, stream);

    dim3 b256(256);

    const int DETN = 131072;
    k_detect<<<dim3(DETN / 256), b256, 0, stream>>>((const unsigned short*)x, cnt, DETN);

    PSrc ps;
    for (int i = 0; i < 17; ++i) ps.p[i] = d_in[3 + i];

    // front-end: in_mfma | cvt | gcount
    k_front<<<dim3(NOTHER), b256, 0, stream>>>(ps, cnt, x, hb, hf8, prm, wt, batch, gcnt);

    // counting-sort CSR (no global atomics)
    k_hist<<<dim3(EB), b256, 0, stream>>>(dst, counts, E);
    k_scanA<<<dim3(NBUCK), b256, 0, stream>>>(counts, bucktot);
    k_scanB<<<1, b256, 0, stream>>>(bucktot, buckBase, rowptr);
    k_scatter<<<dim3(EB), b256, 0, stream>>>(src, dst, counts, buckBase, pairs, E);
    k_bucket<<<dim3(NBUCK), b256, 0, stream>>>(pairs, buckBase, rowptr, dinv, cinv,
                                               csr_src, n);

    int gGemm = (n + 63) / 64;
    int gGath = (n + 3) / 4;
    int gPool = (n + 63) / 64;

    // layer 0 (fp8 gather operand; bf16 self)
    k_gather0<<<gGath, b256, 0, stream>>>(hf8, hb, dinv, cinv, rowptr, csr_src, gb, n);
    k_layer_mfma<<<gGemm, b256, 0, stream>>>(gb, hb, 0,
        wt + 0, wt + 4096, wt + 8192,
        prm + PW_GCNB, prm + PW_SB, prm + PW_GCNBN, prm + PW_SBN, dinv, C1b, C1f8, n);

    // layer 1 (fp8 prescaled gather; bf16 self; bf16 output for pool)
    k_gather1<<<gGath, b256, 0, stream>>>(C1f8, C1b, dinv, cinv, rowptr, csr_src, gb, n);
    k_layer_mfma<<<gGemm, b256, 0, stream>>>(gb, C1b, 1,
        wt + 12288, wt + 16384, wt + 20480,
        prm + PW_GCNB + 64, prm + PW_SB + 64, prm + PW_GCNBN + 256, prm + PW_SBN + 256,
        dinv, C2b, (unsigned short*)nullptr, n);

    // pooling + head
    k_pool2<<<gPool, b256, 0, stream>>>(C2b, batch, pooled, n);
    k_head<<<1, b256, 0, stream>>>(pooled, gcnt, prm, cnt, d_out);
}